// Round 2
// baseline (1445.380 us; speedup 1.0000x reference)
//
#include <hip/hip_runtime.h>
#include <hip/hip_bf16.h>

#define TSEQ 2048
#define NBATCH 8
#define NROWS (NBATCH*TSEQ)   // 16384
#define EMB 128
#define NH 4
#define DH 32
#define FFD 512
#define OUTD 32

// ---------------- build X = concat(kq, v) as fp32 [NROWS x 128] ----------------
__global__ __launch_bounds__(256) void build_x(const float* __restrict__ kq,
                                               const float* __restrict__ v,
                                               float* __restrict__ X){
  int idx = blockIdx.x*256 + threadIdx.x;       // NROWS*128 total
  int row = idx >> 7, c = idx & 127;
  float val = (c < 64) ? kq[row*64 + c] : v[row*64 + (c-64)];
  X[idx] = val;
}

// ---------------- generic GEMM: C = act(A[M x K] @ W[K x N] + bias) ----------------
// A fp32 with row stride lda, W/bias fp32 row-major [K x N], C fp32 [M x N].
// K = 1<<kshift (64/128/512). N multiple of 128. M multiple of 8.
#define GR 8
__global__ __launch_bounds__(128) void gemm_f32(const float* __restrict__ A, int lda, int kshift,
                                                const float* __restrict__ W, const float* __restrict__ bias,
                                                float* __restrict__ C, int Ncols, int act){
  __shared__ float As[GR*512];
  const int Kdim = 1 << kshift;
  const int tid = threadIdx.x;
  const int row0 = blockIdx.x * GR;
  for (int idx = tid; idx < GR*Kdim; idx += 128){
    int r = idx >> kshift;
    int k = idx & (Kdim-1);
    As[idx] = A[(size_t)(row0 + r)*lda + k];
  }
  __syncthreads();
  const int col = blockIdx.y*128 + tid;
  float acc[GR];
  #pragma unroll
  for (int r=0;r<GR;r++) acc[r] = 0.f;
  for (int k=0;k<Kdim;k+=4){
    float w0 = W[(size_t)(k+0)*Ncols + col];
    float w1 = W[(size_t)(k+1)*Ncols + col];
    float w2 = W[(size_t)(k+2)*Ncols + col];
    float w3 = W[(size_t)(k+3)*Ncols + col];
    #pragma unroll
    for (int r=0;r<GR;r++){
      float4 a = *(const float4*)&As[(r<<kshift) + k];
      acc[r] = fmaf(a.x, w0, acc[r]);
      acc[r] = fmaf(a.y, w1, acc[r]);
      acc[r] = fmaf(a.z, w2, acc[r]);
      acc[r] = fmaf(a.w, w3, acc[r]);
    }
  }
  float bv = bias[col];
  #pragma unroll
  for (int r=0;r<GR;r++){
    float vv = acc[r] + bv;
    if (act == 1) vv = 0.5f*vv*(1.f + erff(vv*0.70710678118654752440f));
    C[(size_t)(row0+r)*Ncols + col] = vv;
  }
}

// ---------------- flash attention (fp32, scalar), dh=32, heads packed in cols ----------------
// Q,K,V,O: [NROWS x 128], head h at cols [h*32, h*32+32).
// mode 0: allow j <= i (layer A). mode 1: allow j < i or (i==0 && j==0) (layer B).
#define BQ 64
#define BK 32
__global__ __launch_bounds__(256) void flash_attn(const float* __restrict__ Q,
                                                  const float* __restrict__ K,
                                                  const float* __restrict__ V,
                                                  float* __restrict__ O, int mode){
  __shared__ float Kt[BK*36];   // padded stride 36: conflict-free float4 reads
  __shared__ float Vt[BK*36];
  __shared__ float Pt[BQ*33];   // padded stride 33: conflict-free scalar reads
  const int tid = threadIdx.x;
  const int ql  = tid >> 2;     // 0..63 query within tile
  const int sub = tid & 3;      // 4 threads cooperate per query
  const int bh = blockIdx.y;
  const int b = bh >> 2, h = bh & 3;
  const int q0 = blockIdx.x * BQ;
  const int qg = q0 + ql;

  const float* qptr = Q + ((size_t)(b*TSEQ + qg))*EMB + h*DH;
  float qreg[DH];
  #pragma unroll
  for (int i=0;i<DH;i+=4){
    float4 t = *(const float4*)(qptr + i);
    qreg[i]=t.x; qreg[i+1]=t.y; qreg[i+2]=t.z; qreg[i+3]=t.w;
  }
  float o[8];
  #pragma unroll
  for (int i=0;i<8;i++) o[i]=0.f;
  float m = -3.0e38f, l = 0.f;

  const float* kbase = K + ((size_t)(b*TSEQ))*EMB + h*DH;
  const float* vbase = V + ((size_t)(b*TSEQ))*EMB + h*DH;
  const int jt_max = (q0 + BQ - 1) >> 5;   // inclusive; covers causal range for all rows in tile

  for (int jt = 0; jt <= jt_max; jt++){
    __syncthreads();
    { // stage K,V tile (32x32), 4 floats per thread
      int r = tid >> 3;
      int c = (tid & 7) * 4;
      *(float4*)(&Kt[r*36 + c]) = *(const float4*)(kbase + (size_t)(jt*BK + r)*EMB + c);
      *(float4*)(&Vt[r*36 + c]) = *(const float4*)(vbase + (size_t)(jt*BK + r)*EMB + c);
    }
    __syncthreads();

    // S: this thread handles keys kk = e*4 + sub (spread over banks)
    float p[8];
    float tmax = -3.0e38f;
    #pragma unroll
    for (int e=0;e<8;e++){
      const int kk = e*4 + sub;
      const float* krow = &Kt[kk*36];
      float s = 0.f;
      #pragma unroll
      for (int d=0; d<DH; d+=4){
        float4 kv = *(const float4*)(krow + d);
        s = fmaf(qreg[d+0], kv.x, s);
        s = fmaf(qreg[d+1], kv.y, s);
        s = fmaf(qreg[d+2], kv.z, s);
        s = fmaf(qreg[d+3], kv.w, s);
      }
      const int jg = jt*BK + kk;
      const bool ok = (mode==0) ? (jg <= qg) : ((jg < qg) || (qg==0 && jg==0));
      s = ok ? s : -3.0e38f;
      p[e] = s;
      tmax = fmaxf(tmax, s);
    }
    // row max / sum across the 4 cooperating lanes (same wave)
    tmax = fmaxf(tmax, __shfl_xor(tmax, 1));
    tmax = fmaxf(tmax, __shfl_xor(tmax, 2));
    const float mnew = fmaxf(m, tmax);
    const float alpha = __expf(m - mnew);
    float tsum = 0.f;
    #pragma unroll
    for (int e=0;e<8;e++){
      float pe = (p[e] > -1.0e37f) ? __expf(p[e] - mnew) : 0.f;
      p[e] = pe;
      tsum += pe;
    }
    tsum += __shfl_xor(tsum, 1);
    tsum += __shfl_xor(tsum, 2);
    l = l*alpha + tsum;
    m = mnew;
    #pragma unroll
    for (int e=0;e<8;e++) Pt[ql*33 + e*4 + sub] = p[e];
    #pragma unroll
    for (int i=0;i<8;i++) o[i] *= alpha;
    __syncthreads();
    // PV: o[d] += sum_j P[ql][j] * V[j][sub*8 + d]
    #pragma unroll 4
    for (int j=0;j<BK;j++){
      float pj = Pt[ql*33 + j];
      const float* vrow = &Vt[j*36 + sub*8];
      float4 v0 = *(const float4*)(vrow);
      float4 v1 = *(const float4*)(vrow + 4);
      o[0] = fmaf(pj, v0.x, o[0]); o[1] = fmaf(pj, v0.y, o[1]);
      o[2] = fmaf(pj, v0.z, o[2]); o[3] = fmaf(pj, v0.w, o[3]);
      o[4] = fmaf(pj, v1.x, o[4]); o[5] = fmaf(pj, v1.y, o[5]);
      o[6] = fmaf(pj, v1.z, o[6]); o[7] = fmaf(pj, v1.w, o[7]);
    }
  }
  const float inv = 1.f / l;
  float* optr = O + ((size_t)(b*TSEQ + qg))*EMB + h*DH + sub*8;
  float4 r0 = make_float4(o[0]*inv, o[1]*inv, o[2]*inv, o[3]*inv);
  float4 r1 = make_float4(o[4]*inv, o[5]*inv, o[6]*inv, o[7]*inv);
  *(float4*)(optr)   = r0;
  *(float4*)(optr+4) = r1;
}

// ---------------- LayerNorm with residual: out = LN(X + R) * g + b, D=128 ----------------
__global__ __launch_bounds__(64) void ln_res(const float* __restrict__ X, const float* __restrict__ R,
                                             const float* __restrict__ g, const float* __restrict__ bt,
                                             float* __restrict__ out){
  const int row = blockIdx.x;
  const int tid = threadIdx.x;
  const float* xr = X + (size_t)row*EMB;
  const float* rr = R + (size_t)row*EMB;
  float x0 = xr[tid]    + rr[tid];
  float x1 = xr[tid+64] + rr[tid+64];
  float s  = x0 + x1;
  float s2 = x0*x0 + x1*x1;
  #pragma unroll
  for (int off=1; off<64; off<<=1){
    s  += __shfl_xor(s,  off);
    s2 += __shfl_xor(s2, off);
  }
  float mean = s * (1.f/128.f);
  float var  = s2 * (1.f/128.f) - mean*mean;
  float rstd = rsqrtf(var + 1e-5f);
  out[(size_t)row*EMB + tid]    = (x0-mean)*rstd*g[tid]    + bt[tid];
  out[(size_t)row*EMB + tid+64] = (x1-mean)*rstd*g[tid+64] + bt[tid+64];
}

// ---------------- output head: out[N x 32] = A[N x 128] @ W[128 x 32] + b, fp32 out ----------------
__global__ __launch_bounds__(256) void out_proj(const float* __restrict__ A,
                                                const float* __restrict__ W, const float* __restrict__ bb,
                                                float* __restrict__ out){
  __shared__ float As[8*128];
  __shared__ float Ws[128*32];
  const int tid = threadIdx.x;
  const int row0 = blockIdx.x * 8;
  for (int idx = tid; idx < 8*128; idx += 256) As[idx] = A[(size_t)row0*128 + idx];
  for (int idx = tid; idx < 128*32; idx += 256) Ws[idx] = W[idx];
  __syncthreads();
  const int r = tid >> 5, c = tid & 31;
  float acc = bb[c];
  #pragma unroll 8
  for (int k=0;k<128;k++) acc = fmaf(As[r*128 + k], Ws[k*32 + c], acc);
  out[(size_t)(row0 + r)*OUTD + c] = acc;
}

extern "C" void kernel_launch(void* const* d_in, const int* in_sizes, int n_in,
                              void* d_out, int out_size, void* d_ws, size_t ws_size,
                              hipStream_t stream) {
  const float* kq    = (const float*)d_in[0];
  const float* v     = (const float*)d_in[1];
  const float* A_Wk  = (const float*)d_in[2];  const float* A_bk  = (const float*)d_in[3];
  const float* A_Wq  = (const float*)d_in[4];  const float* A_bq  = (const float*)d_in[5];
  const float* A_Wv  = (const float*)d_in[6];  const float* A_bv  = (const float*)d_in[7];
  const float* A_f1W = (const float*)d_in[8];  const float* A_f1b = (const float*)d_in[9];
  const float* A_f2W = (const float*)d_in[10]; const float* A_f2b = (const float*)d_in[11];
  const float* A_n1g = (const float*)d_in[12]; const float* A_n1b = (const float*)d_in[13];
  const float* A_n2g = (const float*)d_in[14]; const float* A_n2b = (const float*)d_in[15];
  const float* B_Wk  = (const float*)d_in[16]; const float* B_bk  = (const float*)d_in[17];
  const float* B_Wq  = (const float*)d_in[18]; const float* B_bq  = (const float*)d_in[19];
  const float* B_Wv  = (const float*)d_in[20]; const float* B_bv  = (const float*)d_in[21];
  const float* B_f1W = (const float*)d_in[22]; const float* B_f1b = (const float*)d_in[23];
  const float* B_f2W = (const float*)d_in[24]; const float* B_f2b = (const float*)d_in[25];
  const float* out_W = (const float*)d_in[26]; const float* out_b = (const float*)d_in[27];
  float* out = (float*)d_out;

  char* ws = (char*)d_ws;
  const size_t SZ = (size_t)NROWS * 128 * 4;       // 8 MiB per [N x 128] fp32 buffer
  float* X   = (float*)(ws);                       // concat(kq,v) fp32
  float* b1  = (float*)(ws + 1*SZ);                // Qa  / Q2
  float* b2  = (float*)(ws + 2*SZ);                // Ka  / vA
  float* b3  = (float*)(ws + 3*SZ);                // Va  / V2
  float* b4  = (float*)(ws + 4*SZ);                // Oa  / K2
  float* b5  = (float*)(ws + 5*SZ);                // h1  / O2
  float* mid = (float*)(ws + 6*SZ);                // [N x 512] fp32 (32 MiB)
  float* b6  = (float*)(ws + 10*SZ);               // ffo / ff2
  (void)in_sizes; (void)n_in; (void)out_size; (void)ws_size;

  // ---- Layer A ----
  build_x<<<NROWS*128/256, 256, 0, stream>>>(kq, v, X);
  gemm_f32<<<dim3(NROWS/GR, 1), 128, 0, stream>>>(X, 128, 7, A_Wq, A_bq, b1, 128, 0);
  gemm_f32<<<dim3(NROWS/GR, 1), 128, 0, stream>>>(X, 128, 7, A_Wk, A_bk, b2, 128, 0);
  gemm_f32<<<dim3(NROWS/GR, 1), 128, 0, stream>>>(X, 128, 7, A_Wv, A_bv, b3, 128, 0);
  flash_attn<<<dim3(TSEQ/BQ, NBATCH*NH), 256, 0, stream>>>(b1, b2, b3, b4, 0);
  ln_res<<<NROWS, 64, 0, stream>>>(b3, b4, A_n1g, A_n1b, b5);                       // h1
  gemm_f32<<<dim3(NROWS/GR, 4), 128, 0, stream>>>(b5, 128, 7, A_f1W, A_f1b, mid, 512, 1); // gelu
  gemm_f32<<<dim3(NROWS/GR, 1), 128, 0, stream>>>(mid, 512, 9, A_f2W, A_f2b, b6, 128, 0);
  ln_res<<<NROWS, 64, 0, stream>>>(b5, b6, A_n2g, A_n2b, b2);                       // vA

  // ---- Layer B ----
  gemm_f32<<<dim3(NROWS/GR, 1), 128, 0, stream>>>(X, 128, 6, B_Wq, B_bq, b1, 128, 0);  // Q2 (kq = first 64 cols of X)
  gemm_f32<<<dim3(NROWS/GR, 1), 128, 0, stream>>>(X, 128, 6, B_Wk, B_bk, b4, 128, 0);  // K2
  gemm_f32<<<dim3(NROWS/GR, 1), 128, 0, stream>>>(b2, 128, 7, B_Wv, B_bv, b3, 128, 0); // V2
  flash_attn<<<dim3(TSEQ/BQ, NBATCH*NH), 256, 0, stream>>>(b1, b4, b3, b5, 1);
  gemm_f32<<<dim3(NROWS/GR, 4), 128, 0, stream>>>(b5, 128, 7, B_f1W, B_f1b, mid, 512, 1); // gelu
  gemm_f32<<<dim3(NROWS/GR, 1), 128, 0, stream>>>(mid, 512, 9, B_f2W, B_f2b, b6, 128, 0);

  // ---- Output head ----
  out_proj<<<NROWS/8, 256, 0, stream>>>(b6, out_W, out_b, out);
}

// Round 3
// 702.935 us; speedup vs baseline: 2.0562x; 2.0562x over previous
//
#include <hip/hip_runtime.h>
#include <hip/hip_bf16.h>

#define TSEQ 2048
#define NBATCH 8
#define NROWS (NBATCH*TSEQ)   // 16384
#define EMB 128
#define NH 4
#define DH 32
#define FFD 512
#define OUTD 32

typedef short s8v __attribute__((ext_vector_type(8)));
typedef float f4v __attribute__((ext_vector_type(4)));

__device__ __forceinline__ unsigned short f2bf(float f){
  unsigned int u = __float_as_uint(f);
  unsigned int r = u + 0x7fffu + ((u >> 16) & 1u);
  return (unsigned short)(r >> 16);
}

// ---------------- build X = concat(kq, v) as fp32 [NROWS x 128] ----------------
__global__ __launch_bounds__(256) void build_x(const float* __restrict__ kq,
                                               const float* __restrict__ v,
                                               float* __restrict__ X){
  int idx = blockIdx.x*256 + threadIdx.x;       // NROWS*128 total
  int row = idx >> 7, c = idx & 127;
  float val = (c < 64) ? kq[row*64 + c] : v[row*64 + (c-64)];
  X[idx] = val;
}

// ---------------- generic GEMM: C = act(A[M x K] @ W[K x N] + bias) ----------------
#define GR 8
__global__ __launch_bounds__(128) void gemm_f32(const float* __restrict__ A, int lda, int kshift,
                                                const float* __restrict__ W, const float* __restrict__ bias,
                                                float* __restrict__ C, int Ncols, int act){
  __shared__ float As[GR*512];
  const int Kdim = 1 << kshift;
  const int tid = threadIdx.x;
  const int row0 = blockIdx.x * GR;
  for (int idx = tid; idx < GR*Kdim; idx += 128){
    int r = idx >> kshift;
    int k = idx & (Kdim-1);
    As[idx] = A[(size_t)(row0 + r)*lda + k];
  }
  __syncthreads();
  const int col = blockIdx.y*128 + tid;
  float acc[GR];
  #pragma unroll
  for (int r=0;r<GR;r++) acc[r] = 0.f;
  for (int k=0;k<Kdim;k+=4){
    float w0 = W[(size_t)(k+0)*Ncols + col];
    float w1 = W[(size_t)(k+1)*Ncols + col];
    float w2 = W[(size_t)(k+2)*Ncols + col];
    float w3 = W[(size_t)(k+3)*Ncols + col];
    #pragma unroll
    for (int r=0;r<GR;r++){
      float4 a = *(const float4*)&As[(r<<kshift) + k];
      acc[r] = fmaf(a.x, w0, acc[r]);
      acc[r] = fmaf(a.y, w1, acc[r]);
      acc[r] = fmaf(a.z, w2, acc[r]);
      acc[r] = fmaf(a.w, w3, acc[r]);
    }
  }
  float bv = bias[col];
  #pragma unroll
  for (int r=0;r<GR;r++){
    float vv = acc[r] + bv;
    if (act == 1) vv = 0.5f*vv*(1.f + erff(vv*0.70710678118654752440f));
    C[(size_t)(row0+r)*Ncols + col] = vv;
  }
}

// ---------------- MFMA flash attention, dh=32, heads packed in cols ----------------
// Q,K,V,O: [NROWS x 128], head h at cols [h*32, h*32+32).
// Block: 256 threads = 4 waves; each wave owns 16 queries; BK=64 keys per iter.
// mode 0: allow j <= i. mode 1: allow j < i or (i==0 && j==0).
#define KT_STRIDE 40   // bf16 elems; 80 B rows: 16B-aligned frag reads, 2-way banks (free)
#define VT_STRIDE 72   // 144 B rows
#define PW_STRIDE 72
__global__ __launch_bounds__(256) void flash_attn_mfma(const float* __restrict__ Q,
                                                       const float* __restrict__ K,
                                                       const float* __restrict__ V,
                                                       float* __restrict__ O, int mode){
  __shared__ short Kt[64*KT_STRIDE];    // [key][dh] bf16
  __shared__ short Vt[32*VT_STRIDE];    // [dh][key] bf16 (transposed)
  __shared__ short Pw[4][16*PW_STRIDE]; // per-wave P transpose buffer [q][key]
  const int tid  = threadIdx.x;
  const int w    = tid >> 6;
  const int lane = tid & 63;
  const int col  = lane & 15;
  const int quad = lane >> 4;
  const int bh = blockIdx.y;
  const int b = bh >> 2, h = bh & 3;
  const int q0 = blockIdx.x * 64;
  const int qbase = q0 + w*16;

  // Q fragment (A-layout): lane holds Q[qbase+col][quad*8 .. +7]
  s8v qf;
  {
    const float* qptr = Q + ((size_t)(b*TSEQ + qbase + col))*EMB + h*DH + quad*8;
    float4 a0 = *(const float4*)qptr;
    float4 a1 = *(const float4*)(qptr+4);
    qf[0]=(short)f2bf(a0.x); qf[1]=(short)f2bf(a0.y); qf[2]=(short)f2bf(a0.z); qf[3]=(short)f2bf(a0.w);
    qf[4]=(short)f2bf(a1.x); qf[5]=(short)f2bf(a1.y); qf[6]=(short)f2bf(a1.z); qf[7]=(short)f2bf(a1.w);
  }
  f4v o0 = {0.f,0.f,0.f,0.f}, o1 = {0.f,0.f,0.f,0.f};
  float mrow[4] = {-1e30f,-1e30f,-1e30f,-1e30f};
  float lrow[4] = {0.f,0.f,0.f,0.f};

  const float* kbase_g = K + ((size_t)(b*TSEQ))*EMB + h*DH;
  const float* vbase_g = V + ((size_t)(b*TSEQ))*EMB + h*DH;
  const int jtmax = (q0 + 63) >> 6;

  const int kr = tid >> 2;          // staging: key row 0..63
  const int c0 = (tid & 3) * 8;     // staging: dim group {0,8,16,24}

  for (int jt = 0; jt <= jtmax; jt++){
    __syncthreads();
    { // stage K [64x32] and V^T [32x64], fp32 -> bf16
      const float* srck = kbase_g + (size_t)(jt*64 + kr)*EMB + c0;
      float4 x0 = *(const float4*)(srck);
      float4 x1 = *(const float4*)(srck+4);
      s8v kb;
      kb[0]=(short)f2bf(x0.x); kb[1]=(short)f2bf(x0.y); kb[2]=(short)f2bf(x0.z); kb[3]=(short)f2bf(x0.w);
      kb[4]=(short)f2bf(x1.x); kb[5]=(short)f2bf(x1.y); kb[6]=(short)f2bf(x1.z); kb[7]=(short)f2bf(x1.w);
      *(s8v*)&Kt[kr*KT_STRIDE + c0] = kb;
      const float* srcv = vbase_g + (size_t)(jt*64 + kr)*EMB + c0;
      float4 y0 = *(const float4*)(srcv);
      float4 y1 = *(const float4*)(srcv+4);
      Vt[(c0+0)*VT_STRIDE + kr] = (short)f2bf(y0.x);
      Vt[(c0+1)*VT_STRIDE + kr] = (short)f2bf(y0.y);
      Vt[(c0+2)*VT_STRIDE + kr] = (short)f2bf(y0.z);
      Vt[(c0+3)*VT_STRIDE + kr] = (short)f2bf(y0.w);
      Vt[(c0+4)*VT_STRIDE + kr] = (short)f2bf(y1.x);
      Vt[(c0+5)*VT_STRIDE + kr] = (short)f2bf(y1.y);
      Vt[(c0+6)*VT_STRIDE + kr] = (short)f2bf(y1.z);
      Vt[(c0+7)*VT_STRIDE + kr] = (short)f2bf(y1.w);
    }
    __syncthreads();

    // ---- QK^T: 4 key-tiles of 16 ----
    f4v s[4];
    #pragma unroll
    for (int t4=0;t4<4;t4++){
      s8v kf = *(const s8v*)&Kt[(t4*16 + col)*KT_STRIDE + quad*8];
      f4v z = {0.f,0.f,0.f,0.f};
      s[t4] = __builtin_amdgcn_mfma_f32_16x16x32_bf16(qf, kf, z, 0, 0, 0);
    }
    // ---- causal mask (wave-uniform skip for interior tiles) ----
    const int j0 = jt*64;
    if (j0 + 63 >= qbase){
      #pragma unroll
      for (int t4=0;t4<4;t4++){
        const int jg = j0 + t4*16 + col;
        #pragma unroll
        for (int r=0;r<4;r++){
          const int qg = qbase + quad*4 + r;
          const bool ok = (mode==0) ? (jg <= qg) : ((jg < qg) || (qg==0 && jg==0));
          s[t4][r] = ok ? s[t4][r] : -1e30f;
        }
      }
    }
    // ---- online softmax (row = quad*4+r, reduce across 16 lanes of quad) ----
    float alpha[4];
    #pragma unroll
    for (int r=0;r<4;r++){
      float tm = fmaxf(fmaxf(s[0][r],s[1][r]), fmaxf(s[2][r],s[3][r]));
      tm = fmaxf(tm, __shfl_xor(tm,1));
      tm = fmaxf(tm, __shfl_xor(tm,2));
      tm = fmaxf(tm, __shfl_xor(tm,4));
      tm = fmaxf(tm, __shfl_xor(tm,8));
      const float mnew = fmaxf(mrow[r], tm);
      alpha[r] = __expf(mrow[r] - mnew);
      float ts = 0.f;
      #pragma unroll
      for (int t4=0;t4<4;t4++){
        float p = __expf(s[t4][r] - mnew);
        s[t4][r] = p;
        ts += p;
      }
      ts += __shfl_xor(ts,1);
      ts += __shfl_xor(ts,2);
      ts += __shfl_xor(ts,4);
      ts += __shfl_xor(ts,8);
      lrow[r] = lrow[r]*alpha[r] + ts;
      mrow[r] = mnew;
    }
    // ---- P: C-layout -> A-layout via per-wave LDS ----
    #pragma unroll
    for (int r=0;r<4;r++){
      #pragma unroll
      for (int t4=0;t4<4;t4++){
        Pw[w][(quad*4+r)*PW_STRIDE + t4*16 + col] = (short)f2bf(s[t4][r]);
      }
    }
    #pragma unroll
    for (int r=0;r<4;r++){ o0[r]*=alpha[r]; o1[r]*=alpha[r]; }
    // ---- PV: K-dim = 64 keys in two passes of 32 ----
    #pragma unroll
    for (int kk=0;kk<2;kk++){
      s8v pf  = *(const s8v*)&Pw[w][col*PW_STRIDE + kk*32 + quad*8];
      s8v vf0 = *(const s8v*)&Vt[(col)*VT_STRIDE     + kk*32 + quad*8];
      s8v vf1 = *(const s8v*)&Vt[(16+col)*VT_STRIDE  + kk*32 + quad*8];
      o0 = __builtin_amdgcn_mfma_f32_16x16x32_bf16(pf, vf0, o0, 0, 0, 0);
      o1 = __builtin_amdgcn_mfma_f32_16x16x32_bf16(pf, vf1, o1, 0, 0, 0);
    }
  }
  // ---- epilogue: O /= l, write (C-layout scatter, coalesced within quad) ----
  float* obase = O + ((size_t)(b*TSEQ + qbase))*EMB + h*DH;
  #pragma unroll
  for (int r=0;r<4;r++){
    const float inv = 1.f / lrow[r];
    obase[(size_t)(quad*4+r)*EMB + col]      = o0[r]*inv;
    obase[(size_t)(quad*4+r)*EMB + 16 + col] = o1[r]*inv;
  }
}

// ---------------- LayerNorm with residual: out = LN(X + R) * g + b, D=128 ----------------
__global__ __launch_bounds__(64) void ln_res(const float* __restrict__ X, const float* __restrict__ R,
                                             const float* __restrict__ g, const float* __restrict__ bt,
                                             float* __restrict__ out){
  const int row = blockIdx.x;
  const int tid = threadIdx.x;
  const float* xr = X + (size_t)row*EMB;
  const float* rr = R + (size_t)row*EMB;
  float x0 = xr[tid]    + rr[tid];
  float x1 = xr[tid+64] + rr[tid+64];
  float s  = x0 + x1;
  float s2 = x0*x0 + x1*x1;
  #pragma unroll
  for (int off=1; off<64; off<<=1){
    s  += __shfl_xor(s,  off);
    s2 += __shfl_xor(s2, off);
  }
  float mean = s * (1.f/128.f);
  float var  = s2 * (1.f/128.f) - mean*mean;
  float rstd = rsqrtf(var + 1e-5f);
  out[(size_t)row*EMB + tid]    = (x0-mean)*rstd*g[tid]    + bt[tid];
  out[(size_t)row*EMB + tid+64] = (x1-mean)*rstd*g[tid+64] + bt[tid+64];
}

// ---------------- output head: out[N x 32] = A[N x 128] @ W[128 x 32] + b ----------------
__global__ __launch_bounds__(256) void out_proj(const float* __restrict__ A,
                                                const float* __restrict__ W, const float* __restrict__ bb,
                                                float* __restrict__ out){
  __shared__ float As[8*128];
  __shared__ float Ws[128*32];
  const int tid = threadIdx.x;
  const int row0 = blockIdx.x * 8;
  for (int idx = tid; idx < 8*128; idx += 256) As[idx] = A[(size_t)row0*128 + idx];
  for (int idx = tid; idx < 128*32; idx += 256) Ws[idx] = W[idx];
  __syncthreads();
  const int r = tid >> 5, c = tid & 31;
  float acc = bb[c];
  #pragma unroll 8
  for (int k=0;k<128;k++) acc = fmaf(As[r*128 + k], Ws[k*32 + c], acc);
  out[(size_t)(row0 + r)*OUTD + c] = acc;
}

extern "C" void kernel_launch(void* const* d_in, const int* in_sizes, int n_in,
                              void* d_out, int out_size, void* d_ws, size_t ws_size,
                              hipStream_t stream) {
  const float* kq    = (const float*)d_in[0];
  const float* v     = (const float*)d_in[1];
  const float* A_Wk  = (const float*)d_in[2];  const float* A_bk  = (const float*)d_in[3];
  const float* A_Wq  = (const float*)d_in[4];  const float* A_bq  = (const float*)d_in[5];
  const float* A_Wv  = (const float*)d_in[6];  const float* A_bv  = (const float*)d_in[7];
  const float* A_f1W = (const float*)d_in[8];  const float* A_f1b = (const float*)d_in[9];
  const float* A_f2W = (const float*)d_in[10]; const float* A_f2b = (const float*)d_in[11];
  const float* A_n1g = (const float*)d_in[12]; const float* A_n1b = (const float*)d_in[13];
  const float* A_n2g = (const float*)d_in[14]; const float* A_n2b = (const float*)d_in[15];
  const float* B_Wk  = (const float*)d_in[16]; const float* B_bk  = (const float*)d_in[17];
  const float* B_Wq  = (const float*)d_in[18]; const float* B_bq  = (const float*)d_in[19];
  const float* B_Wv  = (const float*)d_in[20]; const float* B_bv  = (const float*)d_in[21];
  const float* B_f1W = (const float*)d_in[22]; const float* B_f1b = (const float*)d_in[23];
  const float* B_f2W = (const float*)d_in[24]; const float* B_f2b = (const float*)d_in[25];
  const float* out_W = (const float*)d_in[26]; const float* out_b = (const float*)d_in[27];
  float* out = (float*)d_out;

  char* ws = (char*)d_ws;
  const size_t SZ = (size_t)NROWS * 128 * 4;       // 8 MiB per [N x 128] fp32 buffer
  float* X   = (float*)(ws);                       // concat(kq,v) fp32
  float* b1  = (float*)(ws + 1*SZ);                // Qa  / Q2
  float* b2  = (float*)(ws + 2*SZ);                // Ka  / vA
  float* b3  = (float*)(ws + 3*SZ);                // Va  / V2
  float* b4  = (float*)(ws + 4*SZ);                // Oa  / K2
  float* b5  = (float*)(ws + 5*SZ);                // h1  / O2
  float* mid = (float*)(ws + 6*SZ);                // [N x 512] fp32 (32 MiB)
  float* b6  = (float*)(ws + 10*SZ);               // ffo / ff2
  (void)in_sizes; (void)n_in; (void)out_size; (void)ws_size;

  // ---- Layer A ----
  build_x<<<NROWS*128/256, 256, 0, stream>>>(kq, v, X);
  gemm_f32<<<dim3(NROWS/GR, 1), 128, 0, stream>>>(X, 128, 7, A_Wq, A_bq, b1, 128, 0);
  gemm_f32<<<dim3(NROWS/GR, 1), 128, 0, stream>>>(X, 128, 7, A_Wk, A_bk, b2, 128, 0);
  gemm_f32<<<dim3(NROWS/GR, 1), 128, 0, stream>>>(X, 128, 7, A_Wv, A_bv, b3, 128, 0);
  flash_attn_mfma<<<dim3(TSEQ/64, NBATCH*NH), 256, 0, stream>>>(b1, b2, b3, b4, 0);
  ln_res<<<NROWS, 64, 0, stream>>>(b3, b4, A_n1g, A_n1b, b5);                       // h1
  gemm_f32<<<dim3(NROWS/GR, 4), 128, 0, stream>>>(b5, 128, 7, A_f1W, A_f1b, mid, 512, 1); // gelu
  gemm_f32<<<dim3(NROWS/GR, 1), 128, 0, stream>>>(mid, 512, 9, A_f2W, A_f2b, b6, 128, 0);
  ln_res<<<NROWS, 64, 0, stream>>>(b5, b6, A_n2g, A_n2b, b2);                       // vA

  // ---- Layer B ----
  gemm_f32<<<dim3(NROWS/GR, 1), 128, 0, stream>>>(X, 128, 6, B_Wq, B_bq, b1, 128, 0);  // Q2
  gemm_f32<<<dim3(NROWS/GR, 1), 128, 0, stream>>>(X, 128, 6, B_Wk, B_bk, b4, 128, 0);  // K2
  gemm_f32<<<dim3(NROWS/GR, 1), 128, 0, stream>>>(b2, 128, 7, B_Wv, B_bv, b3, 128, 0); // V2
  flash_attn_mfma<<<dim3(TSEQ/64, NBATCH*NH), 256, 0, stream>>>(b1, b4, b3, b5, 1);
  gemm_f32<<<dim3(NROWS/GR, 4), 128, 0, stream>>>(b5, 128, 7, B_f1W, B_f1b, mid, 512, 1); // gelu
  gemm_f32<<<dim3(NROWS/GR, 1), 128, 0, stream>>>(mid, 512, 9, B_f2W, B_f2b, b6, 128, 0);

  // ---- Output head ----
  out_proj<<<NROWS/8, 256, 0, stream>>>(b6, out_W, out_b, out);
}

// Round 4
// 404.512 us; speedup vs baseline: 3.5731x; 1.7377x over previous
//
#include <hip/hip_runtime.h>
#include <hip/hip_bf16.h>

#define TSEQ 2048
#define NBATCH 8
#define NROWS (NBATCH*TSEQ)   // 16384
#define EMB 128
#define NH 4
#define DH 32
#define FFD 512
#define OUTD 32

typedef short s8v __attribute__((ext_vector_type(8)));
typedef float f4v __attribute__((ext_vector_type(4)));

__device__ __forceinline__ unsigned short f2bf(float f){
  unsigned int u = __float_as_uint(f);
  unsigned int r = u + 0x7fffu + ((u >> 16) & 1u);
  return (unsigned short)(r >> 16);
}
__device__ __forceinline__ float bf2f(unsigned short u){
  return __uint_as_float(((unsigned int)u) << 16);
}

// ---------------- weight prep: W[K x N] fp32 -> Wt_hi/Wt_lo [N x K] bf16 ----------------
struct WPack {
  const float* src[10];
  int off[10];   // element offset of hi plane in warena; lo at off+kn
  int kn[10];    // K*N
  int nsh[10];   // log2(N)
};
__global__ __launch_bounds__(256) void prep_w(WPack p, short* __restrict__ warena){
  int blk = blockIdx.x;
  int m = 0;
  #pragma unroll
  for (int i=0;i<10;i++){
    int nb = p.kn[i] >> 8;
    if (blk < nb){ m = i; break; }
    blk -= nb;
  }
  int idx = blk*256 + threadIdx.x;       // idx = k*N + n (row-major read, coalesced)
  float x = p.src[m][idx];
  int N1 = (1 << p.nsh[m]) - 1;
  int n = idx & N1;
  int k = idx >> p.nsh[m];
  int K = p.kn[m] >> p.nsh[m];
  unsigned short hi = f2bf(x);
  unsigned short lo = f2bf(x - bf2f(hi));
  short* dst = warena + p.off[m];
  dst[n*K + k]            = (short)hi;
  dst[p.kn[m] + n*K + k]  = (short)lo;
}

// ---------------- MFMA GEMM: C = act(A[M x K] @ W[K x N] + bias) ----------------
// Split-bf16: C ~= Ahi*Whi + Alo*Whi + Ahi*Wlo (fp32-grade accuracy).
// A fp32, optionally concatenated from A0|A1 at column asplit. Wt planes bf16 [N][K].
// Block: 256 thr = 4 waves. BM=64 rows, BN=64 cols (wave w -> cols w*16..+15).
__global__ __launch_bounds__(256) void gemm_mfma(
    const float* __restrict__ A0, const float* __restrict__ A1, int asplit, int lda0, int lda1,
    int K, const short* __restrict__ wt_hi, const short* __restrict__ wt_lo,
    const float* __restrict__ bias, float* __restrict__ Cf, unsigned short* __restrict__ Cb,
    int N, int act){
  __shared__ short As[2][64*40];   // [plane][r*40+c] bf16, stride 40 (2-way banks = free)
  __shared__ short Ws[2][64*40];   // [plane][n*40+k]
  const int tid  = threadIdx.x;
  const int w    = tid >> 6;
  const int lane = tid & 63;
  const int col  = lane & 15;
  const int quad = lane >> 4;
  const int row0 = blockIdx.x * 64;
  const int colbase = blockIdx.y * 64;

  f4v acc[4];
  #pragma unroll
  for (int i=0;i<4;i++) acc[i] = (f4v){0.f,0.f,0.f,0.f};

  const int ar = tid >> 2, ac = (tid & 3)*8;            // A staging: row, col8
  const int wn = tid & 63, wpp = tid >> 6;              // W staging
  const int wpl = wpp >> 1, wh = (wpp & 1)*16;

  for (int k0 = 0; k0 < K; k0 += 32){
    __syncthreads();
    { // stage A tile 64x32 fp32 -> hi/lo bf16
      const int kcol = k0 + ac;
      const float* src = (kcol < asplit)
          ? A0 + (size_t)(row0 + ar)*lda0 + kcol
          : A1 + (size_t)(row0 + ar)*lda1 + (kcol - asplit);
      float4 x0 = *(const float4*)src;
      float4 x1 = *(const float4*)(src + 4);
      float xs[8] = {x0.x,x0.y,x0.z,x0.w,x1.x,x1.y,x1.z,x1.w};
      s8v hi, lo;
      #pragma unroll
      for (int j=0;j<8;j++){
        unsigned short h = f2bf(xs[j]);
        hi[j] = (short)h;
        lo[j] = (short)f2bf(xs[j] - bf2f(h));
      }
      *(s8v*)&As[0][ar*40 + ac] = hi;
      *(s8v*)&As[1][ar*40 + ac] = lo;
    }
    { // stage W tile 64n x 32k bf16 (both planes)
      const short* src = (wpl ? wt_lo : wt_hi) + (size_t)(colbase + wn)*K + k0 + wh;
      *(s8v*)&Ws[wpl][wn*40 + wh]     = *(const s8v*)src;
      *(s8v*)&Ws[wpl][wn*40 + wh + 8] = *(const s8v*)(src + 8);
    }
    __syncthreads();

    s8v bh = *(const s8v*)&Ws[0][(w*16 + col)*40 + quad*8];
    s8v bl = *(const s8v*)&Ws[1][(w*16 + col)*40 + quad*8];
    #pragma unroll
    for (int rt=0;rt<4;rt++){
      s8v ah = *(const s8v*)&As[0][(rt*16 + col)*40 + quad*8];
      s8v al = *(const s8v*)&As[1][(rt*16 + col)*40 + quad*8];
      acc[rt] = __builtin_amdgcn_mfma_f32_16x16x32_bf16(ah, bh, acc[rt], 0, 0, 0);
      acc[rt] = __builtin_amdgcn_mfma_f32_16x16x32_bf16(al, bh, acc[rt], 0, 0, 0);
      acc[rt] = __builtin_amdgcn_mfma_f32_16x16x32_bf16(ah, bl, acc[rt], 0, 0, 0);
    }
  }

  const int colg = colbase + w*16 + col;
  const float bv = bias[colg];
  #pragma unroll
  for (int rt=0;rt<4;rt++){
    #pragma unroll
    for (int r=0;r<4;r++){
      const int row = row0 + rt*16 + quad*4 + r;
      float val = acc[rt][r] + bv;
      if (act == 1) val = 0.5f*val*(1.f + erff(val*0.70710678118654752440f));
      if (Cf) Cf[(size_t)row*N + colg] = val;
      if (Cb) Cb[(size_t)row*N + colg] = f2bf(val);
    }
  }
}

// ---------------- V transpose: V fp32 [NROWS x 128] -> Vt bf16 [BH=32][32 d][2048 t] ----------------
__global__ __launch_bounds__(256) void vtrans(const float* __restrict__ V, unsigned short* __restrict__ Vtb){
  __shared__ short Lt[64*40];
  const int tid = threadIdx.x;
  const int t0 = blockIdx.x * 64;
  const int bh = blockIdx.y;
  const int b = bh >> 2, h = bh & 3;
  {
    const int r = tid >> 2, c = (tid & 3)*8;
    const float* src = V + (size_t)(b*TSEQ + t0 + r)*EMB + h*DH + c;
    float4 x0 = *(const float4*)src;
    float4 x1 = *(const float4*)(src + 4);
    s8v kb;
    kb[0]=(short)f2bf(x0.x); kb[1]=(short)f2bf(x0.y); kb[2]=(short)f2bf(x0.z); kb[3]=(short)f2bf(x0.w);
    kb[4]=(short)f2bf(x1.x); kb[5]=(short)f2bf(x1.y); kb[6]=(short)f2bf(x1.z); kb[7]=(short)f2bf(x1.w);
    *(s8v*)&Lt[r*40 + c] = kb;
  }
  __syncthreads();
  const int d = tid >> 3, kc = (tid & 7)*8;
  s8v o;
  #pragma unroll
  for (int j=0;j<8;j++) o[j] = Lt[(kc + j)*40 + d];
  *(s8v*)(Vtb + ((size_t)bh*32 + d)*TSEQ + t0 + kc) = o;
}

// ---------------- MFMA flash attention, bf16 inputs, dh=32 ----------------
// Qb,Kb: [NROWS x 128] bf16 (head h at cols h*32..). Vtb: [32 bh][32 d][2048 t] bf16.
// Pairing: block bx processes q-tiles {31-bx, bx} -> uniform 33 key-tiles per block.
#define KT_STRIDE 40
#define VT_STRIDE 72
#define PW_STRIDE 72
__global__ __launch_bounds__(256) void flash_attn_mfma(const unsigned short* __restrict__ Qb,
                                                       const unsigned short* __restrict__ Kb,
                                                       const unsigned short* __restrict__ Vtb,
                                                       float* __restrict__ O, int mode){
  __shared__ short Kt[64*KT_STRIDE];
  __shared__ short Vt[32*VT_STRIDE];
  __shared__ short Pw[4][16*PW_STRIDE];
  const int tid  = threadIdx.x;
  const int w    = tid >> 6;
  const int lane = tid & 63;
  const int col  = lane & 15;
  const int quad = lane >> 4;
  const int bh = blockIdx.y;
  const int b = bh >> 2, h = bh & 3;
  const int kr = tid >> 2, kc8 = (tid & 3)*8;   // K staging
  const int vd = tid >> 3, vk8 = (tid & 7)*8;   // V staging

  for (int pass = 0; pass < 2; pass++){
    const int qt = pass ? blockIdx.x : (31 - blockIdx.x);
    const int qbase = qt*64 + w*16;

    s8v qf = *(const s8v*)(Qb + (size_t)(b*TSEQ + qbase + col)*EMB + h*DH + quad*8);
    f4v o0 = {0.f,0.f,0.f,0.f}, o1 = {0.f,0.f,0.f,0.f};
    float mrow[4] = {-1e30f,-1e30f,-1e30f,-1e30f};
    float lrow[4] = {0.f,0.f,0.f,0.f};

    for (int jt = 0; jt <= qt; jt++){
      __syncthreads();
      *(s8v*)&Kt[kr*KT_STRIDE + kc8] =
          *(const s8v*)(Kb + (size_t)(b*TSEQ + jt*64 + kr)*EMB + h*DH + kc8);
      *(s8v*)&Vt[vd*VT_STRIDE + vk8] =
          *(const s8v*)(Vtb + ((size_t)bh*32 + vd)*TSEQ + jt*64 + vk8);
      __syncthreads();

      // ---- QK^T: 4 key-tiles of 16 ----
      f4v s[4];
      #pragma unroll
      for (int t4=0;t4<4;t4++){
        s8v kf = *(const s8v*)&Kt[(t4*16 + col)*KT_STRIDE + quad*8];
        f4v z = {0.f,0.f,0.f,0.f};
        s[t4] = __builtin_amdgcn_mfma_f32_16x16x32_bf16(qf, kf, z, 0, 0, 0);
      }
      // ---- causal mask (only boundary tile needs it) ----
      const int j0 = jt*64;
      if (j0 + 63 >= qbase){
        #pragma unroll
        for (int t4=0;t4<4;t4++){
          const int jg = j0 + t4*16 + col;
          #pragma unroll
          for (int r=0;r<4;r++){
            const int qg = qbase + quad*4 + r;
            const bool ok = (mode==0) ? (jg <= qg) : ((jg < qg) || (qg==0 && jg==0));
            s[t4][r] = ok ? s[t4][r] : -1e30f;
          }
        }
      }
      // ---- online softmax ----
      float alpha[4];
      #pragma unroll
      for (int r=0;r<4;r++){
        float tm = fmaxf(fmaxf(s[0][r],s[1][r]), fmaxf(s[2][r],s[3][r]));
        tm = fmaxf(tm, __shfl_xor(tm,1));
        tm = fmaxf(tm, __shfl_xor(tm,2));
        tm = fmaxf(tm, __shfl_xor(tm,4));
        tm = fmaxf(tm, __shfl_xor(tm,8));
        const float mnew = fmaxf(mrow[r], tm);
        alpha[r] = __expf(mrow[r] - mnew);
        float ts = 0.f;
        #pragma unroll
        for (int t4=0;t4<4;t4++){
          float p = __expf(s[t4][r] - mnew);
          s[t4][r] = p;
          ts += p;
        }
        ts += __shfl_xor(ts,1);
        ts += __shfl_xor(ts,2);
        ts += __shfl_xor(ts,4);
        ts += __shfl_xor(ts,8);
        lrow[r] = lrow[r]*alpha[r] + ts;
        mrow[r] = mnew;
      }
      // ---- P: C-layout -> A-layout via per-wave LDS ----
      #pragma unroll
      for (int r=0;r<4;r++){
        #pragma unroll
        for (int t4=0;t4<4;t4++){
          Pw[w][(quad*4+r)*PW_STRIDE + t4*16 + col] = (short)f2bf(s[t4][r]);
        }
      }
      #pragma unroll
      for (int r=0;r<4;r++){ o0[r]*=alpha[r]; o1[r]*=alpha[r]; }
      // ---- PV ----
      #pragma unroll
      for (int kk=0;kk<2;kk++){
        s8v pf  = *(const s8v*)&Pw[w][col*PW_STRIDE + kk*32 + quad*8];
        s8v vf0 = *(const s8v*)&Vt[(col)*VT_STRIDE    + kk*32 + quad*8];
        s8v vf1 = *(const s8v*)&Vt[(16+col)*VT_STRIDE + kk*32 + quad*8];
        o0 = __builtin_amdgcn_mfma_f32_16x16x32_bf16(pf, vf0, o0, 0, 0, 0);
        o1 = __builtin_amdgcn_mfma_f32_16x16x32_bf16(pf, vf1, o1, 0, 0, 0);
      }
    }
    // ---- epilogue ----
    float* obase = O + (size_t)(b*TSEQ + qbase)*EMB + h*DH;
    #pragma unroll
    for (int r=0;r<4;r++){
      const float inv = 1.f / lrow[r];
      obase[(size_t)(quad*4+r)*EMB + col]      = o0[r]*inv;
      obase[(size_t)(quad*4+r)*EMB + 16 + col] = o1[r]*inv;
    }
  }
}

// ---------------- LayerNorm with residual: out = LN(X + R) * g + b, D=128 ----------------
__global__ __launch_bounds__(64) void ln_res(const float* __restrict__ X, const float* __restrict__ R,
                                             const float* __restrict__ g, const float* __restrict__ bt,
                                             float* __restrict__ out){
  const int row = blockIdx.x;
  const int tid = threadIdx.x;
  const float* xr = X + (size_t)row*EMB;
  const float* rr = R + (size_t)row*EMB;
  float x0 = xr[tid]    + rr[tid];
  float x1 = xr[tid+64] + rr[tid+64];
  float s  = x0 + x1;
  float s2 = x0*x0 + x1*x1;
  #pragma unroll
  for (int off=1; off<64; off<<=1){
    s  += __shfl_xor(s,  off);
    s2 += __shfl_xor(s2, off);
  }
  float mean = s * (1.f/128.f);
  float var  = s2 * (1.f/128.f) - mean*mean;
  float rstd = rsqrtf(var + 1e-5f);
  out[(size_t)row*EMB + tid]    = (x0-mean)*rstd*g[tid]    + bt[tid];
  out[(size_t)row*EMB + tid+64] = (x1-mean)*rstd*g[tid+64] + bt[tid+64];
}

// ---------------- output head: out[N x 32] = A[N x 128] @ W[128 x 32] + b ----------------
__global__ __launch_bounds__(256) void out_proj(const float* __restrict__ A,
                                                const float* __restrict__ W, const float* __restrict__ bb,
                                                float* __restrict__ out){
  __shared__ float As[8*128];
  __shared__ float Ws2[128*32];
  const int tid = threadIdx.x;
  const int row0 = blockIdx.x * 8;
  for (int idx = tid; idx < 8*128; idx += 256) As[idx] = A[(size_t)row0*128 + idx];
  for (int idx = tid; idx < 128*32; idx += 256) Ws2[idx] = W[idx];
  __syncthreads();
  const int r = tid >> 5, c = tid & 31;
  float acc = bb[c];
  #pragma unroll 8
  for (int k=0;k<128;k++) acc = fmaf(As[r*128 + k], Ws2[k*32 + c], acc);
  out[(size_t)(row0 + r)*OUTD + c] = acc;
}

extern "C" void kernel_launch(void* const* d_in, const int* in_sizes, int n_in,
                              void* d_out, int out_size, void* d_ws, size_t ws_size,
                              hipStream_t stream) {
  const float* kq    = (const float*)d_in[0];
  const float* v     = (const float*)d_in[1];
  const float* A_Wk  = (const float*)d_in[2];  const float* A_bk  = (const float*)d_in[3];
  const float* A_Wq  = (const float*)d_in[4];  const float* A_bq  = (const float*)d_in[5];
  const float* A_Wv  = (const float*)d_in[6];  const float* A_bv  = (const float*)d_in[7];
  const float* A_f1W = (const float*)d_in[8];  const float* A_f1b = (const float*)d_in[9];
  const float* A_f2W = (const float*)d_in[10]; const float* A_f2b = (const float*)d_in[11];
  const float* A_n1g = (const float*)d_in[12]; const float* A_n1b = (const float*)d_in[13];
  const float* A_n2g = (const float*)d_in[14]; const float* A_n2b = (const float*)d_in[15];
  const float* B_Wk  = (const float*)d_in[16]; const float* B_bk  = (const float*)d_in[17];
  const float* B_Wq  = (const float*)d_in[18]; const float* B_bq  = (const float*)d_in[19];
  const float* B_Wv  = (const float*)d_in[20]; const float* B_bv  = (const float*)d_in[21];
  const float* B_f1W = (const float*)d_in[22]; const float* B_f1b = (const float*)d_in[23];
  const float* B_f2W = (const float*)d_in[24]; const float* B_f2b = (const float*)d_in[25];
  const float* out_W = (const float*)d_in[26]; const float* out_b = (const float*)d_in[27];
  float* out = (float*)d_out;
  (void)in_sizes; (void)n_in; (void)out_size; (void)ws_size;

  char* ws = (char*)d_ws;
  const size_t MB = 1024*1024;
  short* warena = (short*)ws;                              // [0,8) MB: weight planes (~1.4 MB)
  float* Vf   = (float*)(ws + 8*MB);                       // V fp32 (residual / transpose src)
  float* Obuf = (float*)(ws + 16*MB);                      // attention out fp32
  unsigned short* Vtb = (unsigned short*)(ws + 24*MB);     // V^T bf16 (4 MB), dead before h1 written
  float* h1   = (float*)(ws + 24*MB);                      // overlays Vtb (sequential lifetimes)
  float* mid  = (float*)(ws + 32*MB);                      // FF intermediate [N x 512]
  float* ffo  = (float*)(ws + 64*MB);                      // FF out / ff2
  float* vA   = (float*)(ws + 72*MB);                      // layer-A output
  unsigned short* Qbf = (unsigned short*)(ws + 80*MB);     // bf16 Q
  unsigned short* Kbf = (unsigned short*)(ws + 84*MB);     // bf16 K

  // ---- weight prep ----
  WPack p;
  const float* srcs[10] = {A_Wq,A_Wk,A_Wv,A_f1W,A_f2W,B_Wq,B_Wk,B_Wv,B_f1W,B_f2W};
  int kn[10]  = {16384,16384,16384,65536,65536,8192,8192,16384,65536,65536};
  int nsh[10] = {7,7,7,9,7,7,7,7,9,7};
  int off = 0, offs[10], nblk = 0;
  for (int i=0;i<10;i++){
    p.src[i]=srcs[i]; p.kn[i]=kn[i]; p.nsh[i]=nsh[i];
    offs[i]=off; p.off[i]=off; off += 2*kn[i]; nblk += kn[i] >> 8;
  }
  prep_w<<<nblk, 256, 0, stream>>>(p, warena);
  #define WHI(i) (warena + offs[i])
  #define WLO(i) (warena + offs[i] + kn[i])

  // ---- Layer A ----
  gemm_mfma<<<dim3(256,2), 256, 0, stream>>>(kq, v, 64, 64, 64, 128, WHI(0), WLO(0), A_bq, nullptr, Qbf, 128, 0);
  gemm_mfma<<<dim3(256,2), 256, 0, stream>>>(kq, v, 64, 64, 64, 128, WHI(1), WLO(1), A_bk, nullptr, Kbf, 128, 0);
  gemm_mfma<<<dim3(256,2), 256, 0, stream>>>(kq, v, 64, 64, 64, 128, WHI(2), WLO(2), A_bv, Vf, nullptr, 128, 0);
  vtrans<<<dim3(32,32), 256, 0, stream>>>(Vf, Vtb);
  flash_attn_mfma<<<dim3(16,32), 256, 0, stream>>>(Qbf, Kbf, Vtb, Obuf, 0);
  ln_res<<<NROWS, 64, 0, stream>>>(Vf, Obuf, A_n1g, A_n1b, h1);
  gemm_mfma<<<dim3(256,8), 256, 0, stream>>>(h1, h1, 128, 128, 128, 128, WHI(3), WLO(3), A_f1b, mid, nullptr, 512, 1);
  gemm_mfma<<<dim3(256,2), 256, 0, stream>>>(mid, mid, 512, 512, 512, 512, WHI(4), WLO(4), A_f2b, ffo, nullptr, 128, 0);
  ln_res<<<NROWS, 64, 0, stream>>>(h1, ffo, A_n2g, A_n2b, vA);

  // ---- Layer B ----
  gemm_mfma<<<dim3(256,2), 256, 0, stream>>>(kq, kq, 64, 64, 64, 64, WHI(5), WLO(5), B_bq, nullptr, Qbf, 128, 0);
  gemm_mfma<<<dim3(256,2), 256, 0, stream>>>(kq, kq, 64, 64, 64, 64, WHI(6), WLO(6), B_bk, nullptr, Kbf, 128, 0);
  gemm_mfma<<<dim3(256,2), 256, 0, stream>>>(vA, vA, 128, 128, 128, 128, WHI(7), WLO(7), B_bv, Vf, nullptr, 128, 0);
  vtrans<<<dim3(32,32), 256, 0, stream>>>(Vf, Vtb);
  flash_attn_mfma<<<dim3(16,32), 256, 0, stream>>>(Qbf, Kbf, Vtb, Obuf, 1);
  gemm_mfma<<<dim3(256,8), 256, 0, stream>>>(Obuf, Obuf, 128, 128, 128, 128, WHI(8), WLO(8), B_f1b, mid, nullptr, 512, 1);
  gemm_mfma<<<dim3(256,2), 256, 0, stream>>>(mid, mid, 512, 512, 512, 512, WHI(9), WLO(9), B_f2b, ffo, nullptr, 128, 0);

  // ---- Output head ----
  out_proj<<<NROWS/8, 256, 0, stream>>>(ffo, out_W, out_b, out);
  #undef WHI
  #undef WLO
}

// Round 5
// 316.121 us; speedup vs baseline: 4.5722x; 1.2796x over previous
//
#include <hip/hip_runtime.h>
#include <hip/hip_bf16.h>

#define TSEQ 2048
#define NBATCH 8
#define NROWS (NBATCH*TSEQ)   // 16384
#define EMB 128
#define NH 4
#define DH 32
#define OUTD 32

typedef short s8v __attribute__((ext_vector_type(8)));
typedef float f4v __attribute__((ext_vector_type(4)));

__device__ __forceinline__ unsigned short f2bf(float f){
  unsigned int u = __float_as_uint(f);
  unsigned int r = u + 0x7fffu + ((u >> 16) & 1u);
  return (unsigned short)(r >> 16);
}
__device__ __forceinline__ float bf2f(unsigned short u){
  return __uint_as_float(((unsigned int)u) << 16);
}

// ---------------- weight prep: W[K x N] fp32 -> fused arena [NT][K] hi/lo bf16 ----------------
struct WPack {
  const float* src[10];
  int off[10];     // fused hi-plane base (shorts)
  int ntk[10];     // NT*K of the fused matrix (lo at off+ntk)
  int rowoff[10];  // row offset of this source inside the fused matrix
  int nsh[10];     // log2(N) of source
  int kn[10];      // K*N of source
};
__global__ __launch_bounds__(256) void prep_w(WPack p, short* __restrict__ warena){
  int blk = blockIdx.x, m = 0;
  #pragma unroll
  for (int i=0;i<10;i++){
    int nb = p.kn[i] >> 8;
    if (blk < nb){ m = i; break; }
    blk -= nb;
  }
  int idx = blk*256 + threadIdx.x;       // idx = k*N + n in source
  float x = p.src[m][idx];
  int nsh = p.nsh[m];
  int n = idx & ((1<<nsh)-1);
  int k = idx >> nsh;
  int K = p.kn[m] >> nsh;
  unsigned short hi = f2bf(x);
  unsigned short lo = f2bf(x - bf2f(hi));
  short* dh = warena + p.off[m] + (size_t)(p.rowoff[m] + n)*K + k;
  dh[0]        = (short)hi;
  dh[p.ntk[m]] = (short)lo;
}

// ---------------- pipelined MFMA GEMM ----------------
// C = act(A @ W + bias); A fp32 (split hi/lo, 3 MFMA) or bf16 (2 MFMA).
// W arena [NT][K] bf16, hi at wt, lo at wt+NTK. BM=64, BN=64, double-buffered LDS.
// Output: nseg>1 -> segments of 128 cols with per-seg dtype; else single [*,NT].
struct GOuts {
  const float* bias[3];
  float* of[3];
  unsigned short* ob[3];
};
__global__ __launch_bounds__(256) void gemm2(
    const float* __restrict__ A0, const float* __restrict__ A1,
    const unsigned short* __restrict__ Ab,
    int asplit, int lda0, int lda1, int K, int niter,
    const short* __restrict__ wt, int NTK,
    GOuts og, int NT, int nseg, int act){
  __shared__ short As[2][2][64*40];   // [buf][plane][r*40+c]
  const int tid  = threadIdx.x;
  const int w    = tid >> 6;
  const int lane = tid & 63;
  const int col  = lane & 15;
  const int quad = lane >> 4;
  const int row0 = blockIdx.x * 64;
  const int colg = blockIdx.y*64 + w*16 + col;
  const bool abf = (Ab != nullptr);

  f4v acc[4];
  #pragma unroll
  for (int i=0;i<4;i++) acc[i] = (f4v){0.f,0.f,0.f,0.f};

  const int ar = tid >> 2, ac = (tid & 3)*8;

  float4 pa0, pa1;   // fp32 prefetch
  s8v pab;           // bf16 prefetch
  // preload iter 0
  if (!abf){
    const int kcol = ac;
    const float* src = (kcol < asplit) ? A0 + (size_t)(row0+ar)*lda0 + kcol
                                       : A1 + (size_t)(row0+ar)*lda1 + (kcol - asplit);
    pa0 = *(const float4*)src; pa1 = *(const float4*)(src+4);
  } else {
    pab = *(const s8v*)(Ab + (size_t)(row0+ar)*K + ac);
  }

  for (int i=0;i<niter;i++){
    const int buf = i & 1;
    if (!abf){
      float xs[8] = {pa0.x,pa0.y,pa0.z,pa0.w,pa1.x,pa1.y,pa1.z,pa1.w};
      s8v hi, lo;
      #pragma unroll
      for (int j=0;j<8;j++){
        unsigned short h = f2bf(xs[j]);
        hi[j] = (short)h;
        lo[j] = (short)f2bf(xs[j] - bf2f(h));
      }
      *(s8v*)&As[buf][0][ar*40 + ac] = hi;
      *(s8v*)&As[buf][1][ar*40 + ac] = lo;
    } else {
      *(s8v*)&As[buf][0][ar*40 + ac] = pab;
    }
    __syncthreads();
    if (i+1 < niter){   // prefetch next tile; latency overlaps MFMA section below
      const int kcol = (i+1)*32 + ac;
      if (!abf){
        const float* src = (kcol < asplit) ? A0 + (size_t)(row0+ar)*lda0 + kcol
                                           : A1 + (size_t)(row0+ar)*lda1 + (kcol - asplit);
        pa0 = *(const float4*)src; pa1 = *(const float4*)(src+4);
      } else {
        pab = *(const s8v*)(Ab + (size_t)(row0+ar)*K + kcol);
      }
    }
    const int k0 = i*32;
    const short* wp = wt + (size_t)colg*K + k0 + quad*8;
    s8v bh = *(const s8v*)wp;
    s8v bl = *(const s8v*)(wp + NTK);
    #pragma unroll
    for (int rt=0;rt<4;rt++){
      s8v ah = *(const s8v*)&As[buf][0][(rt*16 + col)*40 + quad*8];
      acc[rt] = __builtin_amdgcn_mfma_f32_16x16x32_bf16(ah, bh, acc[rt], 0, 0, 0);
      if (!abf){
        s8v al = *(const s8v*)&As[buf][1][(rt*16 + col)*40 + quad*8];
        acc[rt] = __builtin_amdgcn_mfma_f32_16x16x32_bf16(al, bh, acc[rt], 0, 0, 0);
      }
      acc[rt] = __builtin_amdgcn_mfma_f32_16x16x32_bf16(ah, bl, acc[rt], 0, 0, 0);
    }
  }

  int seg, lcol, ldc;
  if (nseg > 1){ seg = colg >> 7; lcol = colg & 127; ldc = 128; }
  else         { seg = 0; lcol = colg; ldc = NT; }
  const float bv = og.bias[seg][lcol];
  float* of = og.of[seg];
  unsigned short* ob = og.ob[seg];
  #pragma unroll
  for (int rt=0;rt<4;rt++){
    #pragma unroll
    for (int r=0;r<4;r++){
      const int row = row0 + rt*16 + quad*4 + r;
      float val = acc[rt][r] + bv;
      if (act == 1) val = 0.5f*val*(1.f + erff(val*0.70710678118654752440f));
      if (ob) ob[(size_t)row*ldc + lcol] = f2bf(val);
      else    of[(size_t)row*ldc + lcol] = val;
    }
  }
}

// ---------------- V transpose: V fp32 [NROWS x 128] -> Vt bf16 [32 bh][32 d][2048 t] ----------------
__global__ __launch_bounds__(256) void vtrans(const float* __restrict__ V, unsigned short* __restrict__ Vtb){
  __shared__ short Lt[64*40];
  const int tid = threadIdx.x;
  const int t0 = blockIdx.x * 64;
  const int bh = blockIdx.y;
  const int b = bh >> 2, h = bh & 3;
  {
    const int r = tid >> 2, c = (tid & 3)*8;
    const float* src = V + (size_t)(b*TSEQ + t0 + r)*EMB + h*DH + c;
    float4 x0 = *(const float4*)src;
    float4 x1 = *(const float4*)(src + 4);
    s8v kb;
    kb[0]=(short)f2bf(x0.x); kb[1]=(short)f2bf(x0.y); kb[2]=(short)f2bf(x0.z); kb[3]=(short)f2bf(x0.w);
    kb[4]=(short)f2bf(x1.x); kb[5]=(short)f2bf(x1.y); kb[6]=(short)f2bf(x1.z); kb[7]=(short)f2bf(x1.w);
    *(s8v*)&Lt[r*40 + c] = kb;
  }
  __syncthreads();
  const int d = tid >> 3, kc = (tid & 7)*8;
  s8v o;
  #pragma unroll
  for (int j=0;j<8;j++) o[j] = Lt[(kc + j)*40 + d];
  *(s8v*)(Vtb + ((size_t)bh*32 + d)*TSEQ + t0 + kc) = o;
}

// ---------------- MFMA flash attention v2: no-max softmax, 32q/128thr blocks ----------------
// Qb,Kb: [NROWS x 128] bf16. Vtb: [32 bh][32 d][2048 t] bf16. O fp32.
// Paired q32-tiles (63-bx, bx): 32/33 key-tiles per block, uniform.
#define KT_STRIDE 40
#define VT_STRIDE 72
#define PW_STRIDE 72
__global__ __launch_bounds__(128) void flash2(const unsigned short* __restrict__ Qb,
                                              const unsigned short* __restrict__ Kb,
                                              const unsigned short* __restrict__ Vtb,
                                              float* __restrict__ O, int mode){
  __shared__ short Kt[64*KT_STRIDE];
  __shared__ short Vt[32*VT_STRIDE];
  __shared__ short Pw[2][16*PW_STRIDE];
  const int tid  = threadIdx.x;
  const int w    = tid >> 6;
  const int lane = tid & 63;
  const int col  = lane & 15;
  const int quad = lane >> 4;
  const int bh = blockIdx.y;
  const int b = bh >> 2, h = bh & 3;
  const int kr = tid >> 1, kc16 = (tid & 1)*16;   // K staging: 64 rows x 32 d
  const int vd = tid >> 2, vk16 = (tid & 3)*16;   // V staging: 32 d x 64 k

  for (int pass = 0; pass < 2; pass++){
    const int t = pass ? blockIdx.x : (63 - blockIdx.x);   // heavy tile first
    const int qbase = t*32 + w*16;
    const int jtmax = t >> 1;

    s8v qf = *(const s8v*)(Qb + (size_t)(b*TSEQ + qbase + col)*EMB + h*DH + quad*8);
    f4v o0 = {0.f,0.f,0.f,0.f}, o1 = {0.f,0.f,0.f,0.f};
    float lr[4] = {0.f,0.f,0.f,0.f};

    // preload jt=0
    s8v ka, kb2, va, vb;
    {
      const unsigned short* kp = Kb + (size_t)(b*TSEQ + kr)*EMB + h*DH + kc16;
      ka = *(const s8v*)kp; kb2 = *(const s8v*)(kp + 8);
      const unsigned short* vp = Vtb + ((size_t)bh*32 + vd)*TSEQ + vk16;
      va = *(const s8v*)vp; vb = *(const s8v*)(vp + 8);
    }

    for (int jt = 0; jt <= jtmax; jt++){
      __syncthreads();   // prior readers done
      *(s8v*)&Kt[kr*KT_STRIDE + kc16]     = ka;
      *(s8v*)&Kt[kr*KT_STRIDE + kc16 + 8] = kb2;
      *(s8v*)&Vt[vd*VT_STRIDE + vk16]     = va;
      *(s8v*)&Vt[vd*VT_STRIDE + vk16 + 8] = vb;
      __syncthreads();
      if (jt < jtmax){   // prefetch next tile; overlaps compute below
        const unsigned short* kp = Kb + (size_t)(b*TSEQ + (jt+1)*64 + kr)*EMB + h*DH + kc16;
        ka = *(const s8v*)kp; kb2 = *(const s8v*)(kp + 8);
        const unsigned short* vp = Vtb + ((size_t)bh*32 + vd)*TSEQ + (jt+1)*64 + vk16;
        va = *(const s8v*)vp; vb = *(const s8v*)(vp + 8);
      }

      // ---- QK^T ----
      f4v s[4];
      #pragma unroll
      for (int t4=0;t4<4;t4++){
        s8v kf = *(const s8v*)&Kt[(t4*16 + col)*KT_STRIDE + quad*8];
        f4v z = {0.f,0.f,0.f,0.f};
        s[t4] = __builtin_amdgcn_mfma_f32_16x16x32_bf16(qf, kf, z, 0, 0, 0);
      }
      // ---- causal mask (diagonal tile only) ----
      if (jt == jtmax){
        const int j0 = jt*64;
        #pragma unroll
        for (int t4=0;t4<4;t4++){
          const int jg = j0 + t4*16 + col;
          #pragma unroll
          for (int r=0;r<4;r++){
            const int qg = qbase + quad*4 + r;
            const bool ok = (mode==0) ? (jg <= qg) : ((jg < qg) || (qg==0 && jg==0));
            s[t4][r] = ok ? s[t4][r] : -1e30f;
          }
        }
      }
      // ---- no-max softmax: p = exp(s), accumulate per-lane row sums ----
      #pragma unroll
      for (int t4=0;t4<4;t4++){
        #pragma unroll
        for (int r=0;r<4;r++){
          float pv = __expf(s[t4][r]);    // exp(-1e30) -> 0 for masked
          s[t4][r] = pv;
          lr[r] += pv;
          Pw[w][(quad*4+r)*PW_STRIDE + t4*16 + col] = (short)f2bf(pv);
        }
      }
      // ---- PV ----
      #pragma unroll
      for (int kk=0;kk<2;kk++){
        s8v pf  = *(const s8v*)&Pw[w][col*PW_STRIDE + kk*32 + quad*8];
        s8v vf0 = *(const s8v*)&Vt[(col)*VT_STRIDE    + kk*32 + quad*8];
        s8v vf1 = *(const s8v*)&Vt[(16+col)*VT_STRIDE + kk*32 + quad*8];
        o0 = __builtin_amdgcn_mfma_f32_16x16x32_bf16(pf, vf0, o0, 0, 0, 0);
        o1 = __builtin_amdgcn_mfma_f32_16x16x32_bf16(pf, vf1, o1, 0, 0, 0);
      }
    }
    // ---- epilogue: reduce l across the 16 lanes of the quad, normalize ----
    float* obase = O + (size_t)(b*TSEQ + qbase)*EMB + h*DH;
    #pragma unroll
    for (int r=0;r<4;r++){
      float l = lr[r];
      l += __shfl_xor(l,1); l += __shfl_xor(l,2);
      l += __shfl_xor(l,4); l += __shfl_xor(l,8);
      const float inv = 1.f / l;
      obase[(size_t)(quad*4+r)*EMB + col]      = o0[r]*inv;
      obase[(size_t)(quad*4+r)*EMB + 16 + col] = o1[r]*inv;
    }
  }
}

// ---------------- LayerNorm with residual ----------------
__global__ __launch_bounds__(64) void ln_res(const float* __restrict__ X, const float* __restrict__ R,
                                             const float* __restrict__ g, const float* __restrict__ bt,
                                             float* __restrict__ out){
  const int row = blockIdx.x;
  const int tid = threadIdx.x;
  const float* xr = X + (size_t)row*EMB;
  const float* rr = R + (size_t)row*EMB;
  float x0 = xr[tid]    + rr[tid];
  float x1 = xr[tid+64] + rr[tid+64];
  float s  = x0 + x1;
  float s2 = x0*x0 + x1*x1;
  #pragma unroll
  for (int off=1; off<64; off<<=1){
    s  += __shfl_xor(s,  off);
    s2 += __shfl_xor(s2, off);
  }
  float mean = s * (1.f/128.f);
  float var  = s2 * (1.f/128.f) - mean*mean;
  float rstd = rsqrtf(var + 1e-5f);
  out[(size_t)row*EMB + tid]    = (x0-mean)*rstd*g[tid]    + bt[tid];
  out[(size_t)row*EMB + tid+64] = (x1-mean)*rstd*g[tid+64] + bt[tid+64];
}

// ---------------- output head ----------------
__global__ __launch_bounds__(256) void out_proj(const float* __restrict__ A,
                                                const float* __restrict__ W, const float* __restrict__ bb,
                                                float* __restrict__ out){
  __shared__ float As[8*128];
  __shared__ float Ws2[128*32];
  const int tid = threadIdx.x;
  const int row0 = blockIdx.x * 8;
  for (int idx = tid; idx < 8*128; idx += 256) As[idx] = A[(size_t)row0*128 + idx];
  for (int idx = tid; idx < 128*32; idx += 256) Ws2[idx] = W[idx];
  __syncthreads();
  const int r = tid >> 5, c = tid & 31;
  float acc = bb[c];
  #pragma unroll 8
  for (int k=0;k<128;k++) acc = fmaf(As[r*128 + k], Ws2[k*32 + c], acc);
  out[(size_t)(row0 + r)*OUTD + c] = acc;
}

extern "C" void kernel_launch(void* const* d_in, const int* in_sizes, int n_in,
                              void* d_out, int out_size, void* d_ws, size_t ws_size,
                              hipStream_t stream) {
  const float* kq    = (const float*)d_in[0];
  const float* v     = (const float*)d_in[1];
  const float* A_Wk  = (const float*)d_in[2];  const float* A_bk  = (const float*)d_in[3];
  const float* A_Wq  = (const float*)d_in[4];  const float* A_bq  = (const float*)d_in[5];
  const float* A_Wv  = (const float*)d_in[6];  const float* A_bv  = (const float*)d_in[7];
  const float* A_f1W = (const float*)d_in[8];  const float* A_f1b = (const float*)d_in[9];
  const float* A_f2W = (const float*)d_in[10]; const float* A_f2b = (const float*)d_in[11];
  const float* A_n1g = (const float*)d_in[12]; const float* A_n1b = (const float*)d_in[13];
  const float* A_n2g = (const float*)d_in[14]; const float* A_n2b = (const float*)d_in[15];
  const float* B_Wk  = (const float*)d_in[16]; const float* B_bk  = (const float*)d_in[17];
  const float* B_Wq  = (const float*)d_in[18]; const float* B_bq  = (const float*)d_in[19];
  const float* B_Wv  = (const float*)d_in[20]; const float* B_bv  = (const float*)d_in[21];
  const float* B_f1W = (const float*)d_in[22]; const float* B_f1b = (const float*)d_in[23];
  const float* B_f2W = (const float*)d_in[24]; const float* B_f2b = (const float*)d_in[25];
  const float* out_W = (const float*)d_in[26]; const float* out_b = (const float*)d_in[27];
  float* out = (float*)d_out;
  (void)in_sizes; (void)n_in; (void)out_size; (void)ws_size;

  char* ws = (char*)d_ws;
  const size_t MB = 1024*1024;
  short* warena = (short*)ws;                              // [0,2) MB  (1.32 MB used)
  float* Vf   = (float*)(ws + 2*MB);                       // 8 MB
  float* Obuf = (float*)(ws + 10*MB);                      // 8 MB
  unsigned short* Vtb = (unsigned short*)(ws + 18*MB);     // 4 MB
  float* h1   = (float*)(ws + 22*MB);                      // 8 MB
  unsigned short* mid = (unsigned short*)(ws + 30*MB);     // 16 MB (bf16 [N x 512])
  float* ffo  = (float*)(ws + 46*MB);                      // 8 MB
  float* vA   = (float*)(ws + 54*MB);                      // 8 MB
  unsigned short* Qbf = (unsigned short*)(ws + 62*MB);     // 4 MB
  unsigned short* Kbf = (unsigned short*)(ws + 66*MB);     // 4 MB

  // ---- weight prep: fused matrices [NT][K], hi+lo planes ----
  // QKVA(384x128) F1A(512x128) F2A(128x512) QKB(256x64) VB(128x128) F1B(512x128) F2B(128x512)
  WPack p;
  const float* srcs[10] = {A_Wq,A_Wk,A_Wv,A_f1W,A_f2W,B_Wq,B_Wk,B_Wv,B_f1W,B_f2W};
  int kn[10]     = {16384,16384,16384,65536,65536,8192,8192,16384,65536,65536};
  int nsh[10]    = {7,7,7,9,7,7,7,7,9,7};
  int off[10]    = {0,0,0,98304,229376,360448,360448,393216,425984,557056};
  int ntk[10]    = {49152,49152,49152,65536,65536,16384,16384,16384,65536,65536};
  int rowoff[10] = {0,128,256,0,0,0,128,0,0,0};
  int nblk = 0;
  for (int i=0;i<10;i++){
    p.src[i]=srcs[i]; p.kn[i]=kn[i]; p.nsh[i]=nsh[i];
    p.off[i]=off[i]; p.ntk[i]=ntk[i]; p.rowoff[i]=rowoff[i];
    nblk += kn[i] >> 8;
  }
  prep_w<<<nblk, 256, 0, stream>>>(p, warena);

  GOuts oQKVA = {{A_bq,A_bk,A_bv},{nullptr,nullptr,Vf},{Qbf,Kbf,nullptr}};
  GOuts oF1A  = {{A_f1b,nullptr,nullptr},{nullptr,nullptr,nullptr},{mid,nullptr,nullptr}};
  GOuts oF2A  = {{A_f2b,nullptr,nullptr},{ffo,nullptr,nullptr},{nullptr,nullptr,nullptr}};
  GOuts oQKB  = {{B_bq,B_bk,nullptr},{nullptr,nullptr,nullptr},{Qbf,Kbf,nullptr}};
  GOuts oVB   = {{B_bv,nullptr,nullptr},{Vf,nullptr,nullptr},{nullptr,nullptr,nullptr}};
  GOuts oF1B  = {{B_f1b,nullptr,nullptr},{nullptr,nullptr,nullptr},{mid,nullptr,nullptr}};
  GOuts oF2B  = {{B_f2b,nullptr,nullptr},{ffo,nullptr,nullptr},{nullptr,nullptr,nullptr}};

  // ---- Layer A ----
  gemm2<<<dim3(256,6), 256, 0, stream>>>(kq, v, nullptr, 64, 64, 64, 128, 4,
                                         warena + 0, 49152, oQKVA, 384, 3, 0);
  vtrans<<<dim3(32,32), 256, 0, stream>>>(Vf, Vtb);
  flash2<<<dim3(32,32), 128, 0, stream>>>(Qbf, Kbf, Vtb, Obuf, 0);
  ln_res<<<NROWS, 64, 0, stream>>>(Vf, Obuf, A_n1g, A_n1b, h1);
  gemm2<<<dim3(256,8), 256, 0, stream>>>(h1, h1, nullptr, 128, 128, 128, 128, 4,
                                         warena + 98304, 65536, oF1A, 512, 1, 1);
  gemm2<<<dim3(256,2), 256, 0, stream>>>(nullptr, nullptr, mid, 0, 0, 0, 512, 16,
                                         warena + 229376, 65536, oF2A, 128, 1, 0);
  ln_res<<<NROWS, 64, 0, stream>>>(h1, ffo, A_n2g, A_n2b, vA);

  // ---- Layer B ----
  gemm2<<<dim3(256,4), 256, 0, stream>>>(kq, kq, nullptr, 64, 64, 64, 64, 2,
                                         warena + 360448, 16384, oQKB, 256, 2, 0);
  gemm2<<<dim3(256,2), 256, 0, stream>>>(vA, vA, nullptr, 128, 128, 128, 128, 4,
                                         warena + 393216, 16384, oVB, 128, 1, 0);
  vtrans<<<dim3(32,32), 256, 0, stream>>>(Vf, Vtb);
  flash2<<<dim3(32,32), 128, 0, stream>>>(Qbf, Kbf, Vtb, Obuf, 1);
  gemm2<<<dim3(256,8), 256, 0, stream>>>(Obuf, Obuf, nullptr, 128, 128, 128, 128, 4,
                                         warena + 425984, 65536, oF1B, 512, 1, 1);
  gemm2<<<dim3(256,2), 256, 0, stream>>>(nullptr, nullptr, mid, 0, 0, 0, 512, 16,
                                         warena + 557056, 65536, oF2B, 128, 1, 0);

  // ---- Output head ----
  out_proj<<<NROWS/8, 256, 0, stream>>>(ffo, out_W, out_b, out);
}

// Round 6
// 313.457 us; speedup vs baseline: 4.6111x; 1.0085x over previous
//
#include <hip/hip_runtime.h>
#include <hip/hip_bf16.h>

#define TSEQ 2048
#define NBATCH 8
#define NROWS (NBATCH*TSEQ)   // 16384
#define EMB 128
#define NH 4
#define DH 32
#define OUTD 32
#define APLANE (NROWS*EMB)    // element offset between hi/lo planes (4 MB as bf16)

typedef short s8v __attribute__((ext_vector_type(8)));
typedef float f4v __attribute__((ext_vector_type(4)));

__device__ __forceinline__ unsigned short f2bf(float f){
  unsigned int u = __float_as_uint(f);
  unsigned int r = u + 0x7fffu + ((u >> 16) & 1u);
  return (unsigned short)(r >> 16);
}
__device__ __forceinline__ float bf2f(unsigned short u){
  return __uint_as_float(((unsigned int)u) << 16);
}

// ---------------- weight prep: W[K x N] fp32 -> fused arena [NT][K] hi/lo bf16 ----------------
struct WPack {
  const float* src[10];
  int off[10];     // fused hi-plane base (shorts)
  int ntk[10];     // NT*K of the fused matrix (lo at off+ntk)
  int rowoff[10];  // row offset of this source inside the fused matrix
  int nsh[10];     // log2(N) of source
  int kn[10];      // K*N of source
};
__global__ __launch_bounds__(256) void prep_w(WPack p, short* __restrict__ warena){
  int blk = blockIdx.x, m = 0;
  #pragma unroll
  for (int i=0;i<10;i++){
    int nb = p.kn[i] >> 8;
    if (blk < nb){ m = i; break; }
    blk -= nb;
  }
  int idx = blk*256 + threadIdx.x;       // idx = k*N + n in source
  float x = p.src[m][idx];
  int nsh = p.nsh[m];
  int n = idx & ((1<<nsh)-1);
  int k = idx >> nsh;
  int K = p.kn[m] >> nsh;
  unsigned short hi = f2bf(x);
  unsigned short lo = f2bf(x - bf2f(hi));
  short* dh = warena + p.off[m] + (size_t)(p.rowoff[m] + n)*K + k;
  dh[0]        = (short)hi;
  dh[p.ntk[m]] = (short)lo;
}

// ---------------- X split: concat(kq,v) fp32 -> dual-plane bf16 [NROWS x 128] ----------------
__global__ __launch_bounds__(256) void xsplit(const float* __restrict__ kq, const float* __restrict__ v,
                                              unsigned short* __restrict__ X){
  int idx = blockIdx.x*256 + threadIdx.x;
  int row = idx >> 7, c = idx & 127;
  float val = (c < 64) ? kq[row*64 + c] : v[row*64 + (c-64)];
  unsigned short hi = f2bf(val);
  X[idx]          = hi;
  X[idx + APLANE] = f2bf(val - bf2f(hi));
}

// ---------------- pipelined MFMA GEMM ----------------
// C = act(A @ W + bias). A bf16: dual-plane (aplane>0, 3 MFMA/rt) or single (aplane=0, 2 MFMA/rt).
// W arena [NT][K] bf16, hi at wt, lo at wt+NTK. BM=64, BN=64, double-buffered LDS.
struct GOuts {
  const float* bias[3];
  float* of[3];
  unsigned short* ob[3];
};
__global__ __launch_bounds__(256) void gemm2(
    const unsigned short* __restrict__ A, int aplane, int lda, int K, int niter,
    const short* __restrict__ wt, int NTK,
    GOuts og, int NT, int nseg, int act){
  __shared__ short As[2][2][64*40];   // [buf][plane][r*40+c]
  const int tid  = threadIdx.x;
  const int w    = tid >> 6;
  const int lane = tid & 63;
  const int col  = lane & 15;
  const int quad = lane >> 4;
  const int row0 = blockIdx.x * 64;
  const int colg = blockIdx.y*64 + w*16 + col;
  const bool two = (aplane != 0);

  f4v acc[4];
  #pragma unroll
  for (int i=0;i<4;i++) acc[i] = (f4v){0.f,0.f,0.f,0.f};

  const int ar = tid >> 2, ac = (tid & 3)*8;
  const unsigned short* abase = A + (size_t)(row0 + ar)*lda;

  s8v pah, pal;
  pah = *(const s8v*)(abase + ac);
  if (two) pal = *(const s8v*)(abase + aplane + ac);

  for (int i=0;i<niter;i++){
    const int buf = i & 1;
    *(s8v*)&As[buf][0][ar*40 + ac] = pah;
    if (two) *(s8v*)&As[buf][1][ar*40 + ac] = pal;
    __syncthreads();
    if (i+1 < niter){   // prefetch next tile; latency overlaps MFMA section below
      const int kcol = (i+1)*32 + ac;
      pah = *(const s8v*)(abase + kcol);
      if (two) pal = *(const s8v*)(abase + aplane + kcol);
    }
    const short* wp = wt + (size_t)colg*K + i*32 + quad*8;
    s8v bh = *(const s8v*)wp;
    s8v bl = *(const s8v*)(wp + NTK);
    #pragma unroll
    for (int rt=0;rt<4;rt++){
      s8v ah = *(const s8v*)&As[buf][0][(rt*16 + col)*40 + quad*8];
      acc[rt] = __builtin_amdgcn_mfma_f32_16x16x32_bf16(ah, bh, acc[rt], 0, 0, 0);
      if (two){
        s8v al = *(const s8v*)&As[buf][1][(rt*16 + col)*40 + quad*8];
        acc[rt] = __builtin_amdgcn_mfma_f32_16x16x32_bf16(al, bh, acc[rt], 0, 0, 0);
      }
      acc[rt] = __builtin_amdgcn_mfma_f32_16x16x32_bf16(ah, bl, acc[rt], 0, 0, 0);
    }
  }

  int seg, lcol, ldc;
  if (nseg > 1){ seg = colg >> 7; lcol = colg & 127; ldc = 128; }
  else         { seg = 0; lcol = colg; ldc = NT; }
  const float bv = og.bias[seg][lcol];
  float* of = og.of[seg];
  unsigned short* ob = og.ob[seg];
  #pragma unroll
  for (int rt=0;rt<4;rt++){
    #pragma unroll
    for (int r=0;r<4;r++){
      const int row = row0 + rt*16 + quad*4 + r;
      float val = acc[rt][r] + bv;
      if (act == 1) val = 0.5f*val*(1.f + erff(val*0.70710678118654752440f));
      if (ob) ob[(size_t)row*ldc + lcol] = f2bf(val);
      else    of[(size_t)row*ldc + lcol] = val;
    }
  }
}

// ---------------- V transpose: V fp32 [NROWS x 128] -> Vt bf16 [32 bh][32 d][2048 t] ----------------
__global__ __launch_bounds__(256) void vtrans(const float* __restrict__ V, unsigned short* __restrict__ Vtb){
  __shared__ short Lt[64*40];
  const int tid = threadIdx.x;
  const int t0 = blockIdx.x * 64;
  const int bh = blockIdx.y;
  const int b = bh >> 2, h = bh & 3;
  {
    const int r = tid >> 2, c = (tid & 3)*8;
    const float* src = V + (size_t)(b*TSEQ + t0 + r)*EMB + h*DH + c;
    float4 x0 = *(const float4*)src;
    float4 x1 = *(const float4*)(src + 4);
    s8v kb;
    kb[0]=(short)f2bf(x0.x); kb[1]=(short)f2bf(x0.y); kb[2]=(short)f2bf(x0.z); kb[3]=(short)f2bf(x0.w);
    kb[4]=(short)f2bf(x1.x); kb[5]=(short)f2bf(x1.y); kb[6]=(short)f2bf(x1.z); kb[7]=(short)f2bf(x1.w);
    *(s8v*)&Lt[r*40 + c] = kb;
  }
  __syncthreads();
  const int d = tid >> 3, kc = (tid & 7)*8;
  s8v o;
  #pragma unroll
  for (int j=0;j<8;j++) o[j] = Lt[(kc + j)*40 + d];
  *(s8v*)(Vtb + ((size_t)bh*32 + d)*TSEQ + t0 + kc) = o;
}

// ---------------- split-K MFMA flash attention: no-max softmax, exact partial sums ----------------
// Grid (32 pairs, 32 bh, 2 parity). Block 128 thr = 2 waves, 32 queries.
// Parity z processes key-tiles jt = z, z+2, ... (balanced within 1 tile).
// Outputs UNNORMALIZED partial O into Op[z] and row-sums into Lp[z].
#define KT_STRIDE 40
#define VT_STRIDE 72
#define PW_STRIDE 72
__global__ __launch_bounds__(128) void flash3(const unsigned short* __restrict__ Qb,
                                              const unsigned short* __restrict__ Kb,
                                              const unsigned short* __restrict__ Vtb,
                                              float* __restrict__ O0, float* __restrict__ O1,
                                              float* __restrict__ L0, float* __restrict__ L1,
                                              int mode){
  __shared__ short Kt[64*KT_STRIDE];
  __shared__ short Vt[32*VT_STRIDE];
  __shared__ short Pw[2][16*PW_STRIDE];
  const int tid  = threadIdx.x;
  const int w    = tid >> 6;
  const int lane = tid & 63;
  const int col  = lane & 15;
  const int quad = lane >> 4;
  const int bh = blockIdx.y;
  const int b = bh >> 2, h = bh & 3;
  const int par = blockIdx.z;
  float* Op = par ? O1 : O0;
  float* Lp = par ? L1 : L0;
  const int kr = tid >> 1, kc16 = (tid & 1)*16;   // K staging: 64 rows x 32 d
  const int vd = tid >> 2, vk16 = (tid & 3)*16;   // V staging: 32 d x 64 k

  for (int pass = 0; pass < 2; pass++){
    const int t = pass ? blockIdx.x : (63 - blockIdx.x);   // heavy tile first
    const int qbase = t*32 + w*16;
    const int jtmax = t >> 1;

    s8v qf = *(const s8v*)(Qb + (size_t)(b*TSEQ + qbase + col)*EMB + h*DH + quad*8);
    f4v o0 = {0.f,0.f,0.f,0.f}, o1 = {0.f,0.f,0.f,0.f};
    float lr[4] = {0.f,0.f,0.f,0.f};

    if (par <= jtmax){
      s8v ka, kb2, va, vb;
      {
        const unsigned short* kp = Kb + (size_t)(b*TSEQ + par*64 + kr)*EMB + h*DH + kc16;
        ka = *(const s8v*)kp; kb2 = *(const s8v*)(kp + 8);
        const unsigned short* vp = Vtb + ((size_t)bh*32 + vd)*TSEQ + par*64 + vk16;
        va = *(const s8v*)vp; vb = *(const s8v*)(vp + 8);
      }
      for (int jt = par; jt <= jtmax; jt += 2){
        __syncthreads();
        *(s8v*)&Kt[kr*KT_STRIDE + kc16]     = ka;
        *(s8v*)&Kt[kr*KT_STRIDE + kc16 + 8] = kb2;
        *(s8v*)&Vt[vd*VT_STRIDE + vk16]     = va;
        *(s8v*)&Vt[vd*VT_STRIDE + vk16 + 8] = vb;
        __syncthreads();
        if (jt + 2 <= jtmax){
          const unsigned short* kp = Kb + (size_t)(b*TSEQ + (jt+2)*64 + kr)*EMB + h*DH + kc16;
          ka = *(const s8v*)kp; kb2 = *(const s8v*)(kp + 8);
          const unsigned short* vp = Vtb + ((size_t)bh*32 + vd)*TSEQ + (jt+2)*64 + vk16;
          va = *(const s8v*)vp; vb = *(const s8v*)(vp + 8);
        }
        // ---- QK^T ----
        f4v s[4];
        #pragma unroll
        for (int t4=0;t4<4;t4++){
          s8v kf = *(const s8v*)&Kt[(t4*16 + col)*KT_STRIDE + quad*8];
          f4v z = {0.f,0.f,0.f,0.f};
          s[t4] = __builtin_amdgcn_mfma_f32_16x16x32_bf16(qf, kf, z, 0, 0, 0);
        }
        // ---- causal mask (diagonal tile only) ----
        if (jt == jtmax){
          const int j0 = jt*64;
          #pragma unroll
          for (int t4=0;t4<4;t4++){
            const int jg = j0 + t4*16 + col;
            #pragma unroll
            for (int r=0;r<4;r++){
              const int qg = qbase + quad*4 + r;
              const bool ok = (mode==0) ? (jg <= qg) : ((jg < qg) || (qg==0 && jg==0));
              s[t4][r] = ok ? s[t4][r] : -1e30f;
            }
          }
        }
        // ---- no-max softmax ----
        #pragma unroll
        for (int t4=0;t4<4;t4++){
          #pragma unroll
          for (int r=0;r<4;r++){
            float pv = __expf(s[t4][r]);
            s[t4][r] = pv;
            lr[r] += pv;
            Pw[w][(quad*4+r)*PW_STRIDE + t4*16 + col] = (short)f2bf(pv);
          }
        }
        // ---- PV ----
        #pragma unroll
        for (int kk=0;kk<2;kk++){
          s8v pf  = *(const s8v*)&Pw[w][col*PW_STRIDE + kk*32 + quad*8];
          s8v vf0 = *(const s8v*)&Vt[(col)*VT_STRIDE    + kk*32 + quad*8];
          s8v vf1 = *(const s8v*)&Vt[(16+col)*VT_STRIDE + kk*32 + quad*8];
          o0 = __builtin_amdgcn_mfma_f32_16x16x32_bf16(pf, vf0, o0, 0, 0, 0);
          o1 = __builtin_amdgcn_mfma_f32_16x16x32_bf16(pf, vf1, o1, 0, 0, 0);
        }
      }
    }
    // ---- epilogue: partial row-sum + unnormalized O ----
    float* obase = Op + (size_t)(b*TSEQ + qbase)*EMB + h*DH;
    #pragma unroll
    for (int r=0;r<4;r++){
      float l = lr[r];
      l += __shfl_xor(l,1); l += __shfl_xor(l,2);
      l += __shfl_xor(l,4); l += __shfl_xor(l,8);
      obase[(size_t)(quad*4+r)*EMB + col]      = o0[r];
      obase[(size_t)(quad*4+r)*EMB + 16 + col] = o1[r];
      if (col == 0) Lp[(size_t)(b*TSEQ + qbase + quad*4 + r)*NH + h] = l;
    }
  }
}

// ---------------- combine + residual + LayerNorm (layer A) -> dual-plane bf16 ----------------
__global__ __launch_bounds__(64) void combine_ln(const float* __restrict__ O0, const float* __restrict__ O1,
                                                 const float* __restrict__ L0, const float* __restrict__ L1,
                                                 const float* __restrict__ Vf,
                                                 const float* __restrict__ g, const float* __restrict__ bt,
                                                 unsigned short* __restrict__ outp){
  const int row = blockIdx.x;
  const int tid = threadIdx.x;
  const size_t base = (size_t)row*EMB;
  const int h0 = tid >> 5, h1i = 2 + (tid >> 5);
  const float la = L0[(size_t)row*NH + h0] + L1[(size_t)row*NH + h0];
  const float lb = L0[(size_t)row*NH + h1i] + L1[(size_t)row*NH + h1i];
  float x0 = Vf[base+tid]    + (O0[base+tid]    + O1[base+tid])    / la;
  float x1 = Vf[base+tid+64] + (O0[base+tid+64] + O1[base+tid+64]) / lb;
  float s  = x0 + x1;
  float s2 = x0*x0 + x1*x1;
  #pragma unroll
  for (int off=1; off<64; off<<=1){
    s  += __shfl_xor(s,  off);
    s2 += __shfl_xor(s2, off);
  }
  float mean = s * (1.f/128.f);
  float var  = s2 * (1.f/128.f) - mean*mean;
  float rstd = rsqrtf(var + 1e-5f);
  float y0 = (x0-mean)*rstd*g[tid]    + bt[tid];
  float y1 = (x1-mean)*rstd*g[tid+64] + bt[tid+64];
  unsigned short h0b = f2bf(y0), h1b = f2bf(y1);
  outp[base+tid]             = h0b;
  outp[base+tid+64]          = h1b;
  outp[base+tid+APLANE]      = f2bf(y0 - bf2f(h0b));
  outp[base+tid+64+APLANE]   = f2bf(y1 - bf2f(h1b));
}

// ---------------- residual LN: X dual-plane bf16 + R fp32 -> dual-plane bf16 ----------------
__global__ __launch_bounds__(64) void ln2(const unsigned short* __restrict__ Xp, const float* __restrict__ R,
                                          const float* __restrict__ g, const float* __restrict__ bt,
                                          unsigned short* __restrict__ outp){
  const int row = blockIdx.x;
  const int tid = threadIdx.x;
  const size_t base = (size_t)row*EMB;
  float x0 = bf2f(Xp[base+tid])    + bf2f(Xp[base+tid+APLANE])    + R[base+tid];
  float x1 = bf2f(Xp[base+tid+64]) + bf2f(Xp[base+tid+64+APLANE]) + R[base+tid+64];
  float s  = x0 + x1;
  float s2 = x0*x0 + x1*x1;
  #pragma unroll
  for (int off=1; off<64; off<<=1){
    s  += __shfl_xor(s,  off);
    s2 += __shfl_xor(s2, off);
  }
  float mean = s * (1.f/128.f);
  float var  = s2 * (1.f/128.f) - mean*mean;
  float rstd = rsqrtf(var + 1e-5f);
  float y0 = (x0-mean)*rstd*g[tid]    + bt[tid];
  float y1 = (x1-mean)*rstd*g[tid+64] + bt[tid+64];
  unsigned short h0b = f2bf(y0), h1b = f2bf(y1);
  outp[base+tid]             = h0b;
  outp[base+tid+64]          = h1b;
  outp[base+tid+APLANE]      = f2bf(y0 - bf2f(h0b));
  outp[base+tid+64+APLANE]   = f2bf(y1 - bf2f(h1b));
}

// ---------------- combine (layer B): normalize -> dual-plane bf16 ----------------
__global__ __launch_bounds__(256) void combine_b(const float* __restrict__ O0, const float* __restrict__ O1,
                                                 const float* __restrict__ L0, const float* __restrict__ L1,
                                                 unsigned short* __restrict__ outp){
  const int idx = blockIdx.x*256 + threadIdx.x;
  const int row = idx >> 7, c = idx & 127, h = c >> 5;
  const float l = L0[(size_t)row*NH + h] + L1[(size_t)row*NH + h];
  const float v = (O0[idx] + O1[idx]) / l;
  unsigned short hb = f2bf(v);
  outp[idx]          = hb;
  outp[idx + APLANE] = f2bf(v - bf2f(hb));
}

// ---------------- output head ----------------
__global__ __launch_bounds__(256) void out_proj(const float* __restrict__ A,
                                                const float* __restrict__ W, const float* __restrict__ bb,
                                                float* __restrict__ out){
  __shared__ float As[8*128];
  __shared__ float Ws2[128*32];
  const int tid = threadIdx.x;
  const int row0 = blockIdx.x * 8;
  for (int idx = tid; idx < 8*128; idx += 256) As[idx] = A[(size_t)row0*128 + idx];
  for (int idx = tid; idx < 128*32; idx += 256) Ws2[idx] = W[idx];
  __syncthreads();
  const int r = tid >> 5, c = tid & 31;
  float acc = bb[c];
  #pragma unroll 8
  for (int k=0;k<128;k++) acc = fmaf(As[r*128 + k], Ws2[k*32 + c], acc);
  out[(size_t)(row0 + r)*OUTD + c] = acc;
}

extern "C" void kernel_launch(void* const* d_in, const int* in_sizes, int n_in,
                              void* d_out, int out_size, void* d_ws, size_t ws_size,
                              hipStream_t stream) {
  const float* kq    = (const float*)d_in[0];
  const float* v     = (const float*)d_in[1];
  const float* A_Wk  = (const float*)d_in[2];  const float* A_bk  = (const float*)d_in[3];
  const float* A_Wq  = (const float*)d_in[4];  const float* A_bq  = (const float*)d_in[5];
  const float* A_Wv  = (const float*)d_in[6];  const float* A_bv  = (const float*)d_in[7];
  const float* A_f1W = (const float*)d_in[8];  const float* A_f1b = (const float*)d_in[9];
  const float* A_f2W = (const float*)d_in[10]; const float* A_f2b = (const float*)d_in[11];
  const float* A_n1g = (const float*)d_in[12]; const float* A_n1b = (const float*)d_in[13];
  const float* A_n2g = (const float*)d_in[14]; const float* A_n2b = (const float*)d_in[15];
  const float* B_Wk  = (const float*)d_in[16]; const float* B_bk  = (const float*)d_in[17];
  const float* B_Wq  = (const float*)d_in[18]; const float* B_bq  = (const float*)d_in[19];
  const float* B_Wv  = (const float*)d_in[20]; const float* B_bv  = (const float*)d_in[21];
  const float* B_f1W = (const float*)d_in[22]; const float* B_f1b = (const float*)d_in[23];
  const float* B_f2W = (const float*)d_in[24]; const float* B_f2b = (const float*)d_in[25];
  const float* out_W = (const float*)d_in[26]; const float* out_b = (const float*)d_in[27];
  float* out = (float*)d_out;
  (void)in_sizes; (void)n_in; (void)out_size; (void)ws_size;

  char* ws = (char*)d_ws;
  const size_t MB = 1024*1024;
  short* warena = (short*)ws;                              // 0-2 MB (1.32 MB used)
  unsigned short* Xs  = (unsigned short*)(ws + 2*MB);      // 2-10: X dual-plane bf16
  unsigned short* Qbf = (unsigned short*)(ws + 10*MB);     // 10-14
  unsigned short* Kbf = (unsigned short*)(ws + 14*MB);     // 14-18
  unsigned short* Vtb = (unsigned short*)(ws + 18*MB);     // 18-22
  float* Vf  = (float*)(ws + 22*MB);                       // 22-30
  float* O0  = (float*)(ws + 30*MB);                       // 30-38  (layer A; reused as vA-free zone)
  float* O1  = (float*)(ws + 38*MB);                       // 38-46
  float* L0  = (float*)(ws + 46*MB);                       // 46-47 (256 KB used)
  float* L1  = (float*)(ws + 47*MB);                       // 47-48
  unsigned short* h1p = (unsigned short*)(ws + 48*MB);     // 48-56: h1 dual-plane / ObfB dual-plane
  unsigned short* mid = (unsigned short*)(ws + 56*MB);     // 56-72: bf16 [N x 512]
  float* ffo = (float*)(ws + 72*MB);                       // 72-80
  unsigned short* vAp = (unsigned short*)(ws + 80*MB);     // 80-88: vA dual-plane

  // ---- weight prep: fused matrices [NT][K], hi+lo planes ----
  WPack p;
  const float* srcs[10] = {A_Wq,A_Wk,A_Wv,A_f1W,A_f2W,B_Wq,B_Wk,B_Wv,B_f1W,B_f2W};
  int kn[10]     = {16384,16384,16384,65536,65536,8192,8192,16384,65536,65536};
  int nsh[10]    = {7,7,7,9,7,7,7,7,9,7};
  int off[10]    = {0,0,0,98304,229376,360448,360448,393216,425984,557056};
  int ntk[10]    = {49152,49152,49152,65536,65536,16384,16384,16384,65536,65536};
  int rowoff[10] = {0,128,256,0,0,0,128,0,0,0};
  int nblk = 0;
  for (int i=0;i<10;i++){
    p.src[i]=srcs[i]; p.kn[i]=kn[i]; p.nsh[i]=nsh[i];
    p.off[i]=off[i]; p.ntk[i]=ntk[i]; p.rowoff[i]=rowoff[i];
    nblk += kn[i] >> 8;
  }
  prep_w<<<nblk, 256, 0, stream>>>(p, warena);
  xsplit<<<NROWS*128/256, 256, 0, stream>>>(kq, v, Xs);

  GOuts oQKVA = {{A_bq,A_bk,A_bv},{nullptr,nullptr,Vf},{Qbf,Kbf,nullptr}};
  GOuts oF1A  = {{A_f1b,nullptr,nullptr},{nullptr,nullptr,nullptr},{mid,nullptr,nullptr}};
  GOuts oF2A  = {{A_f2b,nullptr,nullptr},{ffo,nullptr,nullptr},{nullptr,nullptr,nullptr}};
  GOuts oQKB  = {{B_bq,B_bk,nullptr},{nullptr,nullptr,nullptr},{Qbf,Kbf,nullptr}};
  GOuts oVB   = {{B_bv,nullptr,nullptr},{Vf,nullptr,nullptr},{nullptr,nullptr,nullptr}};
  GOuts oF1B  = {{B_f1b,nullptr,nullptr},{nullptr,nullptr,nullptr},{mid,nullptr,nullptr}};
  GOuts oF2B  = {{B_f2b,nullptr,nullptr},{ffo,nullptr,nullptr},{nullptr,nullptr,nullptr}};

  // ---- Layer A ----
  gemm2<<<dim3(256,6), 256, 0, stream>>>(Xs, APLANE, 128, 128, 4, warena + 0,      49152, oQKVA, 384, 3, 0);
  vtrans<<<dim3(32,32), 256, 0, stream>>>(Vf, Vtb);
  flash3<<<dim3(32,32,2), 128, 0, stream>>>(Qbf, Kbf, Vtb, O0, O1, L0, L1, 0);
  combine_ln<<<NROWS, 64, 0, stream>>>(O0, O1, L0, L1, Vf, A_n1g, A_n1b, h1p);
  gemm2<<<dim3(256,8), 256, 0, stream>>>(h1p, APLANE, 128, 128, 4, warena + 98304, 65536, oF1A, 512, 1, 1);
  gemm2<<<dim3(256,2), 256, 0, stream>>>(mid, 0,      512, 512, 16, warena + 229376, 65536, oF2A, 128, 1, 0);
  ln2<<<NROWS, 64, 0, stream>>>(h1p, ffo, A_n2g, A_n2b, vAp);

  // ---- Layer B ----
  gemm2<<<dim3(256,4), 256, 0, stream>>>(Xs, APLANE, 128, 64, 2,  warena + 360448, 16384, oQKB, 256, 2, 0);
  gemm2<<<dim3(256,2), 256, 0, stream>>>(vAp, APLANE, 128, 128, 4, warena + 393216, 16384, oVB, 128, 1, 0);
  vtrans<<<dim3(32,32), 256, 0, stream>>>(Vf, Vtb);
  flash3<<<dim3(32,32,2), 128, 0, stream>>>(Qbf, Kbf, Vtb, O0, O1, L0, L1, 1);
  combine_b<<<NROWS*128/256, 256, 0, stream>>>(O0, O1, L0, L1, h1p);
  gemm2<<<dim3(256,8), 256, 0, stream>>>(h1p, APLANE, 128, 128, 4, warena + 425984, 65536, oF1B, 512, 1, 1);
  gemm2<<<dim3(256,2), 256, 0, stream>>>(mid, 0,      512, 512, 16, warena + 557056, 65536, oF2B, 128, 1, 0);

  // ---- Output head ----
  out_proj<<<NROWS/8, 256, 0, stream>>>(ffo, out_W, out_b, out);
}